// Round 4
// baseline (610.554 us; speedup 1.0000x reference)
//
#include <hip/hip_runtime.h>

#define N_NODES 100000
#define N_EDGES 1600000
#define BKT_SHIFT 13
#define BKT_SIZE 8192
#define NB 196  // ceil(N_EDGES / BKT_SIZE)

constexpr float NEG_SLOPE = 0.2f;

__device__ __forceinline__ float leaky(float x) { return x > 0.f ? x : NEG_SLOPE * x; }

// bf16 pack/unpack (RNE)
__device__ __forceinline__ unsigned bfpack2(float a, float b) {
    unsigned ua = __float_as_uint(a), ub = __float_as_uint(b);
    ua = (ua + 0x7fffu + ((ua >> 16) & 1u)) >> 16;
    ub = (ub + 0x7fffu + ((ub >> 16) & 1u)) >> 16;
    return ua | (ub << 16);
}
__device__ __forceinline__ float bflo(unsigned u) { return __uint_as_float(u << 16); }
__device__ __forceinline__ float bfhi(unsigned u) { return __uint_as_float(u & 0xffff0000u); }

// ---------------- CSR build (counting sort by dst, no random global writes) ----------------
__global__ void count_rank_kernel(const int* __restrict__ dst, int* __restrict__ counts,
                                  unsigned short* __restrict__ rank, int E) {
    int i = blockIdx.x * blockDim.x + threadIdx.x;
    if (i < E) rank[i] = (unsigned short)atomicAdd(&counts[dst[i]], 1);
}

__global__ void scan1_kernel(const int* __restrict__ counts, int* __restrict__ row_ptr,
                             int* __restrict__ partials, int N) {
    __shared__ int sh[1024];
    int tid = threadIdx.x;
    int i = blockIdx.x * 1024 + tid;
    int v = (i < N) ? counts[i] : 0;
    sh[tid] = v;
    __syncthreads();
    for (int off = 1; off < 1024; off <<= 1) {
        int t = (tid >= off) ? sh[tid - off] : 0;
        __syncthreads();
        sh[tid] += t;
        __syncthreads();
    }
    if (i < N) row_ptr[i] = sh[tid] - v;
    if (tid == 1023) partials[blockIdx.x] = sh[tid];
}

__global__ void scan2_kernel(int* partials, int nb) {
    if (threadIdx.x == 0 && blockIdx.x == 0) {
        int run = 0;
        for (int i = 0; i < nb; ++i) { int v = partials[i]; partials[i] = run; run += v; }
    }
}

__global__ void scan3_kernel(int* __restrict__ row_ptr, const int* __restrict__ partials,
                             int N, int E) {
    int i = blockIdx.x * 1024 + threadIdx.x;
    if (i < N) row_ptr[i] += partials[blockIdx.x];
    if (i == 0) row_ptr[N] = E;
}

__global__ __launch_bounds__(256) void partition_kernel(
        const int* __restrict__ src, const int* __restrict__ dst,
        const unsigned short* __restrict__ rank, const int* __restrict__ row_ptr,
        int* __restrict__ bucket_cursor, unsigned* __restrict__ staged, int E) {
    __shared__ unsigned pos_s[4096];
    __shared__ unsigned stage[4096];
    __shared__ unsigned char bkt_s[4096];
    __shared__ unsigned hist[256];
    __shared__ unsigned scanb[256];
    __shared__ unsigned baseg[256];
    __shared__ unsigned cnt[256];
    int tid = threadIdx.x;
    int e0 = blockIdx.x * 4096;
    hist[tid] = 0;
    cnt[tid] = 0;
    __syncthreads();
#pragma unroll
    for (int k = 0; k < 16; ++k) {
        int idx = k * 256 + tid;
        int i = e0 + idx;
        unsigned p = 0u;
        if (i < E) {
            int d = dst[i];
            p = (unsigned)(row_ptr[d] + (int)rank[i]);
            atomicAdd(&hist[p >> BKT_SHIFT], 1u);
        }
        pos_s[idx] = p;
    }
    __syncthreads();
    unsigned v = hist[tid];
    scanb[tid] = v;
    __syncthreads();
    for (int off = 1; off < 256; off <<= 1) {
        unsigned t = (tid >= off) ? scanb[tid - off] : 0;
        __syncthreads();
        scanb[tid] += t;
        __syncthreads();
    }
    unsigned excl = scanb[tid] - v;
    __syncthreads();
    scanb[tid] = excl;
    if (tid < NB)
        baseg[tid] = (unsigned)(tid * BKT_SIZE) + (unsigned)atomicAdd(&bucket_cursor[tid], (int)v);
    __syncthreads();
#pragma unroll
    for (int k = 0; k < 16; ++k) {
        int idx = k * 256 + tid;
        int i = e0 + idx;
        if (i < E) {
            unsigned p = pos_s[idx];
            unsigned b = p >> BKT_SHIFT;
            unsigned slot = scanb[b] + atomicAdd(&cnt[b], 1u);
            stage[slot] = ((p & (BKT_SIZE - 1)) << 17) | (unsigned)src[i];
            bkt_s[slot] = (unsigned char)b;
        }
    }
    __syncthreads();
    int total = min(4096, E - e0);
    for (int j = tid; j < total; j += 256) {
        unsigned b = bkt_s[j];
        unsigned addr = baseg[b] + ((unsigned)j - scanb[b]);
        staged[addr] = stage[j];
    }
}

__global__ __launch_bounds__(256) void bucket_kernel(const unsigned* __restrict__ staged,
                                                     int* __restrict__ csr_src, int E) {
    __shared__ int lsrc[BKT_SIZE];
    int base = blockIdx.x * BKT_SIZE;
    int count = min(BKT_SIZE, E - base);
    for (int j = threadIdx.x; j < count; j += 256) {
        unsigned pl = staged[base + j];
        lsrc[pl >> 17] = (int)(pl & 0x1FFFFu);
    }
    __syncthreads();
    const int4* ls4 = reinterpret_cast<const int4*>(lsrc);
    int4* out4 = reinterpret_cast<int4*>(csr_src + base);
    int c4 = count >> 2;
    for (int j = threadIdx.x; j < c4; j += 256) out4[j] = ls4[j];
    for (int j = (c4 << 2) + threadIdx.x; j < count; j += 256) csr_src[base + j] = lsrc[j];
}

// ---------------- LDS-tiled fp32 GEMM + el/er epilogue + bf16 feat store ----------------
// Block handles TM rows x DOUT cols; thread = 4 rows x 4 cols register tile.
// tid = cp + CP*rp, CP = DOUT/4, threads BT = CP*TM/4.
template <int DIN, int DOUT, int TM, int CP, int BT, int XSTR, int OSTR>
__global__ __launch_bounds__(BT) void gemm_tile_kernel(
        const float* __restrict__ X, const float* __restrict__ W,
        const float* __restrict__ al, const float* __restrict__ ar,
        unsigned short* __restrict__ featb, float* __restrict__ el,
        float* __restrict__ er, int N) {
    __shared__ float Xs[TM * XSTR];
    __shared__ float Ws[DIN * DOUT];
    int tid = threadIdx.x;
    int n0 = blockIdx.x * TM;
    int cp = tid % CP;
    int rp = tid / CP;

    // stage X tile (guarded) and W
    constexpr int XT4 = TM * DIN / 4;
    for (int idx = tid; idx < XT4; idx += BT) {
        int row = idx / (DIN / 4);
        int c4 = idx % (DIN / 4);
        float4 v = make_float4(0.f, 0.f, 0.f, 0.f);
        if (n0 + row < N)
            v = reinterpret_cast<const float4*>(X + (size_t)(n0 + row) * DIN)[c4];
        *reinterpret_cast<float4*>(&Xs[row * XSTR + 4 * c4]) = v;
    }
    constexpr int WT4 = DIN * DOUT / 4;
    for (int idx = tid; idx < WT4; idx += BT)
        *reinterpret_cast<float4*>(&Ws[idx * 4]) = reinterpret_cast<const float4*>(W)[idx];
    __syncthreads();

    int r0 = 4 * rp;
    float4 acc4[4];
#pragma unroll
    for (int r = 0; r < 4; ++r) acc4[r] = make_float4(0.f, 0.f, 0.f, 0.f);

    for (int k4 = 0; k4 < DIN / 4; ++k4) {
        float4 w0 = *reinterpret_cast<const float4*>(&Ws[(4 * k4 + 0) * DOUT + 4 * cp]);
        float4 w1 = *reinterpret_cast<const float4*>(&Ws[(4 * k4 + 1) * DOUT + 4 * cp]);
        float4 w2 = *reinterpret_cast<const float4*>(&Ws[(4 * k4 + 2) * DOUT + 4 * cp]);
        float4 w3 = *reinterpret_cast<const float4*>(&Ws[(4 * k4 + 3) * DOUT + 4 * cp]);
#pragma unroll
        for (int r = 0; r < 4; ++r) {
            float4 xv = *reinterpret_cast<const float4*>(&Xs[(r0 + r) * XSTR + 4 * k4]);
            acc4[r].x += xv.x * w0.x + xv.y * w1.x + xv.z * w2.x + xv.w * w3.x;
            acc4[r].y += xv.x * w0.y + xv.y * w1.y + xv.z * w2.y + xv.w * w3.y;
            acc4[r].z += xv.x * w0.z + xv.y * w1.z + xv.z * w2.z + xv.w * w3.z;
            acc4[r].w += xv.x * w0.w + xv.y * w1.w + xv.z * w2.w + xv.w * w3.w;
        }
    }

    // feat store (bf16)
#pragma unroll
    for (int r = 0; r < 4; ++r) {
        int grow = n0 + r0 + r;
        if (grow < N) {
            uint2 pk;
            pk.x = bfpack2(acc4[r].x, acc4[r].y);
            pk.y = bfpack2(acc4[r].z, acc4[r].w);
            *reinterpret_cast<uint2*>(&featb[(size_t)grow * OSTR + 4 * cp]) = pk;
        }
    }

    // el/er epilogue
    float4 alv = *reinterpret_cast<const float4*>(&al[4 * cp]);
    float4 arv = *reinterpret_cast<const float4*>(&ar[4 * cp]);
    float pel[4], per[4];
#pragma unroll
    for (int r = 0; r < 4; ++r) {
        pel[r] = acc4[r].x * alv.x + acc4[r].y * alv.y + acc4[r].z * alv.z + acc4[r].w * alv.w;
        per[r] = acc4[r].x * arv.x + acc4[r].y * arv.y + acc4[r].z * arv.z + acc4[r].w * arv.w;
    }
    if constexpr (CP == 16) {
        // 16 col-threads per row are 16 consecutive, group-aligned lanes -> shuffle reduce
#pragma unroll
        for (int o = 1; o < 16; o <<= 1) {
#pragma unroll
            for (int r = 0; r < 4; ++r) {
                pel[r] += __shfl_xor(pel[r], o, 64);
                per[r] += __shfl_xor(per[r], o, 64);
            }
        }
        if (cp == 0) {
#pragma unroll
            for (int r = 0; r < 4; ++r) {
                int grow = n0 + r0 + r;
                if (grow < N) { el[grow] = pel[r]; er[grow] = per[r]; }
            }
        }
    } else {
        __shared__ float els[TM];
        __shared__ float ers[TM];
        for (int i = tid; i < TM; i += BT) { els[i] = 0.f; ers[i] = 0.f; }
        __syncthreads();
#pragma unroll
        for (int r = 0; r < 4; ++r) {
            atomicAdd(&els[r0 + r], pel[r]);
            atomicAdd(&ers[r0 + r], per[r]);
        }
        __syncthreads();
        for (int i = tid; i < TM; i += BT) {
            if (n0 + i < N) { el[n0 + i] = els[i]; er[n0 + i] = ers[i]; }
        }
    }
}

// ---------------- Segment softmax + aggregation (bf16 gather, fp32 math) ----------------
template <int DOUT, int FSTR, int OSTR, bool ELU>
__global__ void agg_kernel(const int* __restrict__ row_ptr, const int* __restrict__ csr_src,
                           const float* __restrict__ el, const float* __restrict__ er,
                           const unsigned short* __restrict__ featb,
                           const float* __restrict__ bias, float* __restrict__ outp, int N) {
    int lane = threadIdx.x & 63;
    int n = blockIdx.x * (blockDim.x >> 6) + (threadIdx.x >> 6);
    if (n >= N) return;
    int beg = row_ptr[n];
    int end = row_ptr[n + 1];
    int deg = end - beg;
    float ern = er[n];

    constexpr int G2 = DOUT / 4;  // uint2 (4 bf16) chunks per row: 16 (64), 10 (40)

    if (deg <= 64) {
        int s = 0;
        float e = -1e30f;
        bool act = lane < deg;
        if (act) {
            s = csr_src[beg + lane];
            e = leaky(el[s] + ern);
        }
        float m = e;
#pragma unroll
        for (int o = 32; o > 0; o >>= 1) m = fmaxf(m, __shfl_xor(m, o, 64));
        float ee = act ? __expf(e - m) : 0.f;
        float ssum = ee;
#pragma unroll
        for (int o = 32; o > 0; o >>= 1) ssum += __shfl_xor(ssum, o, 64);

        int g = lane >> 4;
        int cl = lane & 15;
        float4 acc = make_float4(0.f, 0.f, 0.f, 0.f);
        int niter = (deg + 3) >> 2;
        for (int i = 0; i < niter; i += 2) {
            int e0 = 4 * i + g;
            int e1 = e0 + 4;
            float w0 = __shfl(ee, e0 & 63, 64);
            int s0 = __shfl(s, e0 & 63, 64);
            float w1 = __shfl(ee, e1 & 63, 64);
            int s1 = __shfl(s, e1 & 63, 64);
            if (e0 >= deg) w0 = 0.f;
            if (e1 >= deg) w1 = 0.f;
            if (cl < G2) {
                uint2 q0 = *(reinterpret_cast<const uint2*>(featb + (size_t)s0 * FSTR) + cl);
                uint2 q1 = *(reinterpret_cast<const uint2*>(featb + (size_t)s1 * FSTR) + cl);
                acc.x += w0 * bflo(q0.x) + w1 * bflo(q1.x);
                acc.y += w0 * bfhi(q0.x) + w1 * bfhi(q1.x);
                acc.z += w0 * bflo(q0.y) + w1 * bflo(q1.y);
                acc.w += w0 * bfhi(q0.y) + w1 * bfhi(q1.y);
            }
        }
#pragma unroll
        for (int o = 16; o <= 32; o <<= 1) {
            acc.x += __shfl_xor(acc.x, o, 64);
            acc.y += __shfl_xor(acc.y, o, 64);
            acc.z += __shfl_xor(acc.z, o, 64);
            acc.w += __shfl_xor(acc.w, o, 64);
        }
        if (g == 0 && cl < G2) {
            float inv = (deg > 0) ? 1.f / ssum : 0.f;
            const float4 b4 = reinterpret_cast<const float4*>(bias)[cl];
            float4 o4;
            o4.x = acc.x * inv + b4.x;
            o4.y = acc.y * inv + b4.y;
            o4.z = acc.z * inv + b4.z;
            o4.w = acc.w * inv + b4.w;
            if (ELU) {
                o4.x = o4.x > 0.f ? o4.x : (__expf(o4.x) - 1.f);
                o4.y = o4.y > 0.f ? o4.y : (__expf(o4.y) - 1.f);
                o4.z = o4.z > 0.f ? o4.z : (__expf(o4.z) - 1.f);
                o4.w = o4.w > 0.f ? o4.w : (__expf(o4.w) - 1.f);
            }
            *reinterpret_cast<float4*>(outp + (size_t)n * OSTR + 4 * cl) = o4;
        }
        return;
    }

    // slow path (deg > 64)
    float m = -1e30f;
    for (int j = beg + lane; j < end; j += 64) {
        float e = leaky(el[csr_src[j]] + ern);
        m = fmaxf(m, e);
    }
#pragma unroll
    for (int o = 32; o > 0; o >>= 1) m = fmaxf(m, __shfl_xor(m, o, 64));

    float ssum = 0.f;
    float acc = 0.f;
    for (int base = beg; base < end; base += 64) {
        int j = base + lane;
        int cnt = min(64, end - base);
        int s = (lane < cnt) ? csr_src[j] : 0;
        float ee = 0.f;
        if (lane < cnt) {
            float e = leaky(el[s] + ern);
            ee = __expf(e - m);
        }
        ssum += ee;
        for (int t = 0; t < cnt; ++t) {
            float w = __shfl(ee, t, 64);
            int sj = __shfl(s, t, 64);
            if (lane < DOUT)
                acc += w * __uint_as_float(((unsigned)featb[(size_t)sj * FSTR + lane]) << 16);
        }
    }
#pragma unroll
    for (int o = 32; o > 0; o >>= 1) ssum += __shfl_xor(ssum, o, 64);

    if (lane < DOUT) {
        float o = acc / ssum + bias[lane];
        if (ELU) o = (o > 0.f) ? o : (__expf(o) - 1.f);
        outp[(size_t)n * OSTR + lane] = o;
    }
}

extern "C" void kernel_launch(void* const* d_in, const int* in_sizes, int n_in,
                              void* d_out, int out_size, void* d_ws, size_t ws_size,
                              hipStream_t stream) {
    const float* in_feat = (const float*)d_in[0];
    const int* src = (const int*)d_in[1];
    const int* dst = (const int*)d_in[2];
    const float* W1 = (const float*)d_in[3];
    const float* al1 = (const float*)d_in[4];
    const float* ar1 = (const float*)d_in[5];
    const float* b1 = (const float*)d_in[6];
    const float* W2 = (const float*)d_in[7];
    const float* al2 = (const float*)d_in[8];
    const float* ar2 = (const float*)d_in[9];
    const float* b2 = (const float*)d_in[10];
    float* out = (float*)d_out;

    const int N = N_NODES, E = N_EDGES;
    const int E_PAD = NB * BKT_SIZE;

    size_t off = 0;
    auto carve = [&](size_t bytes) {
        void* p = (char*)d_ws + off;
        off += (bytes + 255) & ~(size_t)255;
        return p;
    };
    // long-lived
    unsigned short* featb = (unsigned short*)carve((size_t)N * 64 * 2);  // bf16 gather table (both layers)
    float* el    = (float*)carve((size_t)N * 4);
    float* er    = (float*)carve((size_t)N * 4);
    int* row_ptr = (int*)carve((size_t)(N + 1) * 4);
    int* csr_src = (int*)carve((size_t)E * 4);
    int* bucket_cursor = (int*)carve((size_t)NB * 4);
    // h overlaps the CSR-build temporaries (all dead before agg1 writes h)
    size_t offH = off;
    float* h = (float*)carve((size_t)N * 64 * 4);
    size_t off_end = off;
    off = offH;
    unsigned short* rank = (unsigned short*)carve((size_t)E * 2);
    unsigned* staged     = (unsigned*)carve((size_t)E_PAD * 4);
    int* counts          = (int*)carve((size_t)N * 4);
    int* partials        = (int*)carve(1024 * 4);
    off = off_end;

    hipMemsetAsync(counts, 0, (size_t)N * 4, stream);
    hipMemsetAsync(bucket_cursor, 0, (size_t)NB * 4, stream);

    int egrid = (E + 255) / 256;
    count_rank_kernel<<<egrid, 256, 0, stream>>>(dst, counts, rank, E);
    int nb = (N + 1023) / 1024;
    scan1_kernel<<<nb, 1024, 0, stream>>>(counts, row_ptr, partials, N);
    scan2_kernel<<<1, 64, 0, stream>>>(partials, nb);
    scan3_kernel<<<nb, 1024, 0, stream>>>(row_ptr, partials, N, E);
    int pgrid = (E + 4095) / 4096;
    partition_kernel<<<pgrid, 256, 0, stream>>>(src, dst, rank, row_ptr, bucket_cursor, staged, E);
    bucket_kernel<<<NB, 256, 0, stream>>>(staged, csr_src, E);

    int agrid = (N + 3) / 4;

    // layer 1: tiled GEMM (TM=64, 256 thr, Xs 32KB + Ws 32KB = 64KB LDS)
    gemm_tile_kernel<128, 64, 64, 16, 256, 128, 64>
        <<<(N + 63) / 64, 256, 0, stream>>>(in_feat, W1, al1, ar1, featb, el, er, N);
    agg_kernel<64, 64, 64, true><<<agrid, 256, 0, stream>>>(row_ptr, csr_src, el, er, featb, b1, h, N);

    // layer 2: tiled GEMM (TM=128, 320 thr, Xs 128x68 + Ws 10KB + els/ers = 46KB LDS)
    gemm_tile_kernel<64, 40, 128, 10, 320, 68, 40>
        <<<(N + 127) / 128, 320, 0, stream>>>(h, W2, al2, ar2, featb, el, er, N);
    agg_kernel<40, 40, 40, false><<<agrid, 256, 0, stream>>>(row_ptr, csr_src, el, er, featb, b2, out, N);
}

// Round 5
// 567.645 us; speedup vs baseline: 1.0756x; 1.0756x over previous
//
#include <hip/hip_runtime.h>

#define N_NODES 100000
#define N_EDGES 1600000
#define BKT_SHIFT 13
#define BKT_SIZE 8192
#define NB 196  // ceil(N_EDGES / BKT_SIZE)

constexpr float NEG_SLOPE = 0.2f;

__device__ __forceinline__ float leaky(float x) { return x > 0.f ? x : NEG_SLOPE * x; }

// bf16 pack/unpack (RNE)
__device__ __forceinline__ unsigned bfpack2(float a, float b) {
    unsigned ua = __float_as_uint(a), ub = __float_as_uint(b);
    ua = (ua + 0x7fffu + ((ua >> 16) & 1u)) >> 16;
    ub = (ub + 0x7fffu + ((ub >> 16) & 1u)) >> 16;
    return ua | (ub << 16);
}
__device__ __forceinline__ float bflo(unsigned u) { return __uint_as_float(u << 16); }
__device__ __forceinline__ float bfhi(unsigned u) { return __uint_as_float(u & 0xffff0000u); }

// ---------------- CSR build (counting sort by dst, no random global writes) ----------------
__global__ void count_rank_kernel(const int* __restrict__ dst, int* __restrict__ counts,
                                  unsigned short* __restrict__ rank, int E) {
    int i = blockIdx.x * blockDim.x + threadIdx.x;
    if (i < E) rank[i] = (unsigned short)atomicAdd(&counts[dst[i]], 1);
}

__global__ void scan1_kernel(const int* __restrict__ counts, int* __restrict__ row_ptr,
                             int* __restrict__ partials, int N) {
    __shared__ int sh[1024];
    int tid = threadIdx.x;
    int i = blockIdx.x * 1024 + tid;
    int v = (i < N) ? counts[i] : 0;
    sh[tid] = v;
    __syncthreads();
    for (int off = 1; off < 1024; off <<= 1) {
        int t = (tid >= off) ? sh[tid - off] : 0;
        __syncthreads();
        sh[tid] += t;
        __syncthreads();
    }
    if (i < N) row_ptr[i] = sh[tid] - v;
    if (tid == 1023) partials[blockIdx.x] = sh[tid];
}

__global__ void scan2_kernel(int* partials, int nb) {
    if (threadIdx.x == 0 && blockIdx.x == 0) {
        int run = 0;
        for (int i = 0; i < nb; ++i) { int v = partials[i]; partials[i] = run; run += v; }
    }
}

__global__ void scan3_kernel(int* __restrict__ row_ptr, const int* __restrict__ partials,
                             int N, int E) {
    int i = blockIdx.x * 1024 + threadIdx.x;
    if (i < N) row_ptr[i] += partials[blockIdx.x];
    if (i == 0) row_ptr[N] = E;
}

__global__ __launch_bounds__(256) void partition_kernel(
        const int* __restrict__ src, const int* __restrict__ dst,
        const unsigned short* __restrict__ rank, const int* __restrict__ row_ptr,
        int* __restrict__ bucket_cursor, unsigned* __restrict__ staged, int E) {
    __shared__ unsigned pos_s[4096];
    __shared__ unsigned stage[4096];
    __shared__ unsigned char bkt_s[4096];
    __shared__ unsigned hist[256];
    __shared__ unsigned scanb[256];
    __shared__ unsigned baseg[256];
    __shared__ unsigned cnt[256];
    int tid = threadIdx.x;
    int e0 = blockIdx.x * 4096;
    hist[tid] = 0;
    cnt[tid] = 0;
    __syncthreads();
#pragma unroll
    for (int k = 0; k < 16; ++k) {
        int idx = k * 256 + tid;
        int i = e0 + idx;
        unsigned p = 0u;
        if (i < E) {
            int d = dst[i];
            p = (unsigned)(row_ptr[d] + (int)rank[i]);
            atomicAdd(&hist[p >> BKT_SHIFT], 1u);
        }
        pos_s[idx] = p;
    }
    __syncthreads();
    unsigned v = hist[tid];
    scanb[tid] = v;
    __syncthreads();
    for (int off = 1; off < 256; off <<= 1) {
        unsigned t = (tid >= off) ? scanb[tid - off] : 0;
        __syncthreads();
        scanb[tid] += t;
        __syncthreads();
    }
    unsigned excl = scanb[tid] - v;
    __syncthreads();
    scanb[tid] = excl;
    if (tid < NB)
        baseg[tid] = (unsigned)(tid * BKT_SIZE) + (unsigned)atomicAdd(&bucket_cursor[tid], (int)v);
    __syncthreads();
#pragma unroll
    for (int k = 0; k < 16; ++k) {
        int idx = k * 256 + tid;
        int i = e0 + idx;
        if (i < E) {
            unsigned p = pos_s[idx];
            unsigned b = p >> BKT_SHIFT;
            unsigned slot = scanb[b] + atomicAdd(&cnt[b], 1u);
            stage[slot] = ((p & (BKT_SIZE - 1)) << 17) | (unsigned)src[i];
            bkt_s[slot] = (unsigned char)b;
        }
    }
    __syncthreads();
    int total = min(4096, E - e0);
    for (int j = tid; j < total; j += 256) {
        unsigned b = bkt_s[j];
        unsigned addr = baseg[b] + ((unsigned)j - scanb[b]);
        staged[addr] = stage[j];
    }
}

__global__ __launch_bounds__(256) void bucket_kernel(const unsigned* __restrict__ staged,
                                                     int* __restrict__ csr_src, int E) {
    __shared__ int lsrc[BKT_SIZE];
    int base = blockIdx.x * BKT_SIZE;
    int count = min(BKT_SIZE, E - base);
    for (int j = threadIdx.x; j < count; j += 256) {
        unsigned pl = staged[base + j];
        lsrc[pl >> 17] = (int)(pl & 0x1FFFFu);
    }
    __syncthreads();
    const int4* ls4 = reinterpret_cast<const int4*>(lsrc);
    int4* out4 = reinterpret_cast<int4*>(csr_src + base);
    int c4 = count >> 2;
    for (int j = threadIdx.x; j < c4; j += 256) out4[j] = ls4[j];
    for (int j = (c4 << 2) + threadIdx.x; j < count; j += 256) csr_src[base + j] = lsrc[j];
}

// ---------------- Column-split row GEMM + el/er epilogue + bf16 feat store ----------------
// SPLIT consecutive threads share one row; each computes CPT = DOUT/SPLIT columns.
template <int DIN, int DOUT, int SPLIT, int OSTR>
__global__ void gemm_split_kernel(const float* __restrict__ X, const float* __restrict__ W,
                                  const float* __restrict__ al, const float* __restrict__ ar,
                                  unsigned short* __restrict__ featb, float* __restrict__ el,
                                  float* __restrict__ er, int N) {
    constexpr int CPT = DOUT / SPLIT;
    int gid = blockIdx.x * blockDim.x + threadIdx.x;
    int r = gid / SPLIT;
    int q = gid % SPLIT;
    if (r >= N) return;
    int c0 = q * CPT;

    float acc[CPT];
#pragma unroll
    for (int c = 0; c < CPT; ++c) acc[c] = 0.f;

    const float4* X4 = reinterpret_cast<const float4*>(X + (size_t)r * DIN);
    for (int k4 = 0; k4 < DIN / 4; ++k4) {
        float4 xv4 = X4[k4];
        float xv[4] = {xv4.x, xv4.y, xv4.z, xv4.w};
#pragma unroll
        for (int kk = 0; kk < 4; ++kk) {
            const float4* wr = reinterpret_cast<const float4*>(W + (size_t)(4 * k4 + kk) * DOUT + c0);
#pragma unroll
            for (int c4 = 0; c4 < CPT / 4; ++c4) {
                float4 w = wr[c4];
                acc[c4 * 4 + 0] += xv[kk] * w.x;
                acc[c4 * 4 + 1] += xv[kk] * w.y;
                acc[c4 * 4 + 2] += xv[kk] * w.z;
                acc[c4 * 4 + 3] += xv[kk] * w.w;
            }
        }
    }

    // el/er partials + cross-lane combine (row's SPLIT threads are adjacent, aligned lanes)
    float elv = 0.f, erv = 0.f;
#pragma unroll
    for (int c = 0; c < CPT; ++c) { elv += acc[c] * al[c0 + c]; erv += acc[c] * ar[c0 + c]; }
#pragma unroll
    for (int o = 1; o < SPLIT; o <<= 1) {
        elv += __shfl_xor(elv, o, 64);
        erv += __shfl_xor(erv, o, 64);
    }
    if (q == 0) { el[r] = elv; er[r] = erv; }

    // bf16 feat store: CPT shorts at featb[r*OSTR + c0] (byte offsets 8B-aligned for both layers)
    unsigned short* fp = featb + (size_t)r * OSTR + c0;
#pragma unroll
    for (int c4 = 0; c4 < CPT / 4; ++c4) {
        uint2 pk;
        pk.x = bfpack2(acc[c4 * 4 + 0], acc[c4 * 4 + 1]);
        pk.y = bfpack2(acc[c4 * 4 + 2], acc[c4 * 4 + 3]);
        *reinterpret_cast<uint2*>(fp + 4 * c4) = pk;
    }
}

// ---------------- Segment softmax + aggregation (bf16 gather, fp32 math) ----------------
template <int DOUT, int FSTR, int OSTR, bool ELU>
__global__ void agg_kernel(const int* __restrict__ row_ptr, const int* __restrict__ csr_src,
                           const float* __restrict__ el, const float* __restrict__ er,
                           const unsigned short* __restrict__ featb,
                           const float* __restrict__ bias, float* __restrict__ outp, int N) {
    int lane = threadIdx.x & 63;
    int n = blockIdx.x * (blockDim.x >> 6) + (threadIdx.x >> 6);
    if (n >= N) return;
    int beg = row_ptr[n];
    int end = row_ptr[n + 1];
    int deg = end - beg;
    float ern = er[n];

    constexpr int G2 = DOUT / 4;  // uint2 (4 bf16) chunks per row

    if (deg <= 64) {
        int s = 0;
        float e = -1e30f;
        bool act = lane < deg;
        if (act) {
            s = csr_src[beg + lane];
            e = leaky(el[s] + ern);
        }
        float m = e;
#pragma unroll
        for (int o = 32; o > 0; o >>= 1) m = fmaxf(m, __shfl_xor(m, o, 64));
        float ee = act ? __expf(e - m) : 0.f;
        float ssum = ee;
#pragma unroll
        for (int o = 32; o > 0; o >>= 1) ssum += __shfl_xor(ssum, o, 64);

        int g = lane >> 4;
        int cl = lane & 15;
        float4 acc = make_float4(0.f, 0.f, 0.f, 0.f);
        int niter = (deg + 3) >> 2;
        for (int i = 0; i < niter; i += 2) {
            int e0 = 4 * i + g;
            int e1 = e0 + 4;
            float w0 = __shfl(ee, e0 & 63, 64);
            int s0 = __shfl(s, e0 & 63, 64);
            float w1 = __shfl(ee, e1 & 63, 64);
            int s1 = __shfl(s, e1 & 63, 64);
            if (e0 >= deg) w0 = 0.f;
            if (e1 >= deg) w1 = 0.f;
            if (cl < G2) {
                uint2 q0 = *(reinterpret_cast<const uint2*>(featb + (size_t)s0 * FSTR) + cl);
                uint2 q1 = *(reinterpret_cast<const uint2*>(featb + (size_t)s1 * FSTR) + cl);
                acc.x += w0 * bflo(q0.x) + w1 * bflo(q1.x);
                acc.y += w0 * bfhi(q0.x) + w1 * bfhi(q1.x);
                acc.z += w0 * bflo(q0.y) + w1 * bflo(q1.y);
                acc.w += w0 * bfhi(q0.y) + w1 * bfhi(q1.y);
            }
        }
#pragma unroll
        for (int o = 16; o <= 32; o <<= 1) {
            acc.x += __shfl_xor(acc.x, o, 64);
            acc.y += __shfl_xor(acc.y, o, 64);
            acc.z += __shfl_xor(acc.z, o, 64);
            acc.w += __shfl_xor(acc.w, o, 64);
        }
        if (g == 0 && cl < G2) {
            float inv = (deg > 0) ? 1.f / ssum : 0.f;
            const float4 b4 = reinterpret_cast<const float4*>(bias)[cl];
            float4 o4;
            o4.x = acc.x * inv + b4.x;
            o4.y = acc.y * inv + b4.y;
            o4.z = acc.z * inv + b4.z;
            o4.w = acc.w * inv + b4.w;
            if (ELU) {
                o4.x = o4.x > 0.f ? o4.x : (__expf(o4.x) - 1.f);
                o4.y = o4.y > 0.f ? o4.y : (__expf(o4.y) - 1.f);
                o4.z = o4.z > 0.f ? o4.z : (__expf(o4.z) - 1.f);
                o4.w = o4.w > 0.f ? o4.w : (__expf(o4.w) - 1.f);
            }
            *reinterpret_cast<float4*>(outp + (size_t)n * OSTR + 4 * cl) = o4;
        }
        return;
    }

    // slow path (deg > 64)
    float m = -1e30f;
    for (int j = beg + lane; j < end; j += 64) {
        float e = leaky(el[csr_src[j]] + ern);
        m = fmaxf(m, e);
    }
#pragma unroll
    for (int o = 32; o > 0; o >>= 1) m = fmaxf(m, __shfl_xor(m, o, 64));

    float ssum = 0.f;
    float acc = 0.f;
    for (int base = beg; base < end; base += 64) {
        int j = base + lane;
        int cnt = min(64, end - base);
        int s = (lane < cnt) ? csr_src[j] : 0;
        float ee = 0.f;
        if (lane < cnt) {
            float e = leaky(el[s] + ern);
            ee = __expf(e - m);
        }
        ssum += ee;
        for (int t = 0; t < cnt; ++t) {
            float w = __shfl(ee, t, 64);
            int sj = __shfl(s, t, 64);
            if (lane < DOUT)
                acc += w * __uint_as_float(((unsigned)featb[(size_t)sj * FSTR + lane]) << 16);
        }
    }
#pragma unroll
    for (int o = 32; o > 0; o >>= 1) ssum += __shfl_xor(ssum, o, 64);

    if (lane < DOUT) {
        float o = acc / ssum + bias[lane];
        if (ELU) o = (o > 0.f) ? o : (__expf(o) - 1.f);
        outp[(size_t)n * OSTR + lane] = o;
    }
}

extern "C" void kernel_launch(void* const* d_in, const int* in_sizes, int n_in,
                              void* d_out, int out_size, void* d_ws, size_t ws_size,
                              hipStream_t stream) {
    const float* in_feat = (const float*)d_in[0];
    const int* src = (const int*)d_in[1];
    const int* dst = (const int*)d_in[2];
    const float* W1 = (const float*)d_in[3];
    const float* al1 = (const float*)d_in[4];
    const float* ar1 = (const float*)d_in[5];
    const float* b1 = (const float*)d_in[6];
    const float* W2 = (const float*)d_in[7];
    const float* al2 = (const float*)d_in[8];
    const float* ar2 = (const float*)d_in[9];
    const float* b2 = (const float*)d_in[10];
    float* out = (float*)d_out;

    const int N = N_NODES, E = N_EDGES;
    const int E_PAD = NB * BKT_SIZE;

    size_t off = 0;
    auto carve = [&](size_t bytes) {
        void* p = (char*)d_ws + off;
        off += (bytes + 255) & ~(size_t)255;
        return p;
    };
    // long-lived
    unsigned short* featb = (unsigned short*)carve((size_t)N * 64 * 2);  // bf16 gather table (both layers)
    float* el    = (float*)carve((size_t)N * 4);
    float* er    = (float*)carve((size_t)N * 4);
    int* row_ptr = (int*)carve((size_t)(N + 1) * 4);
    int* csr_src = (int*)carve((size_t)E * 4);
    int* bucket_cursor = (int*)carve((size_t)NB * 4);
    // h overlaps the CSR-build temporaries (all dead before agg1 writes h)
    size_t offH = off;
    float* h = (float*)carve((size_t)N * 64 * 4);
    size_t off_end = off;
    off = offH;
    unsigned short* rank = (unsigned short*)carve((size_t)E * 2);
    unsigned* staged     = (unsigned*)carve((size_t)E_PAD * 4);
    int* counts          = (int*)carve((size_t)N * 4);
    int* partials        = (int*)carve(1024 * 4);
    off = off_end;

    hipMemsetAsync(counts, 0, (size_t)N * 4, stream);
    hipMemsetAsync(bucket_cursor, 0, (size_t)NB * 4, stream);

    int egrid = (E + 255) / 256;
    count_rank_kernel<<<egrid, 256, 0, stream>>>(dst, counts, rank, E);
    int nb = (N + 1023) / 1024;
    scan1_kernel<<<nb, 1024, 0, stream>>>(counts, row_ptr, partials, N);
    scan2_kernel<<<1, 64, 0, stream>>>(partials, nb);
    scan3_kernel<<<nb, 1024, 0, stream>>>(row_ptr, partials, N, E);
    int pgrid = (E + 4095) / 4096;
    partition_kernel<<<pgrid, 256, 0, stream>>>(src, dst, rank, row_ptr, bucket_cursor, staged, E);
    bucket_kernel<<<NB, 256, 0, stream>>>(staged, csr_src, E);

    int agrid = (N + 3) / 4;

    // layer 1: SPLIT=4 (16 cols/thread), 400K threads
    gemm_split_kernel<128, 64, 4, 64>
        <<<(4 * N + 255) / 256, 256, 0, stream>>>(in_feat, W1, al1, ar1, featb, el, er, N);
    agg_kernel<64, 64, 64, true><<<agrid, 256, 0, stream>>>(row_ptr, csr_src, el, er, featb, b1, h, N);

    // layer 2: SPLIT=2 (20 cols/thread), 200K threads; featb stride 40
    gemm_split_kernel<64, 40, 2, 40>
        <<<(2 * N + 255) / 256, 256, 0, stream>>>(h, W2, al2, ar2, featb, el, er, N);
    agg_kernel<40, 40, 40, false><<<agrid, 256, 0, stream>>>(row_ptr, csr_src, el, er, featb, b2, out, N);
}

// Round 6
// 374.387 us; speedup vs baseline: 1.6308x; 1.5162x over previous
//
#include <hip/hip_runtime.h>

#define N_NODES 100000
#define N_EDGES 1600000
#define BKT_SHIFT 13
#define BKT_SIZE 8192
#define NB 196  // ceil(N_EDGES / BKT_SIZE)

constexpr float NEG_SLOPE = 0.2f;

__device__ __forceinline__ float leaky(float x) { return x > 0.f ? x : NEG_SLOPE * x; }

// bf16 pack/unpack (RNE)
__device__ __forceinline__ unsigned bfpack2(float a, float b) {
    unsigned ua = __float_as_uint(a), ub = __float_as_uint(b);
    ua = (ua + 0x7fffu + ((ua >> 16) & 1u)) >> 16;
    ub = (ub + 0x7fffu + ((ub >> 16) & 1u)) >> 16;
    return ua | (ub << 16);
}
__device__ __forceinline__ float bflo(unsigned u) { return __uint_as_float(u << 16); }
__device__ __forceinline__ float bfhi(unsigned u) { return __uint_as_float(u & 0xffff0000u); }

// split fp32 -> bf16 hi (truncate) + bf16 lo (RNE of residual); x ~= hi + lo with ~2^-16 rel err
__device__ __forceinline__ void bfsplit(float x, short& h, short& l) {
    unsigned u = __float_as_uint(x);
    h = (short)(u >> 16);
    float res = x - __uint_as_float(u & 0xffff0000u);
    unsigned r = __float_as_uint(res);
    r = (r + 0x7fffu + ((r >> 16) & 1u)) >> 16;
    l = (short)r;
}

// ---------------- CSR build (counting sort by dst, no random global writes) ----------------
__global__ void count_rank_kernel(const int* __restrict__ dst, int* __restrict__ counts,
                                  unsigned short* __restrict__ rank, int E) {
    int i = blockIdx.x * blockDim.x + threadIdx.x;
    if (i < E) rank[i] = (unsigned short)atomicAdd(&counts[dst[i]], 1);
}

__global__ void scan1_kernel(const int* __restrict__ counts, int* __restrict__ row_ptr,
                             int* __restrict__ partials, int N) {
    __shared__ int sh[1024];
    int tid = threadIdx.x;
    int i = blockIdx.x * 1024 + tid;
    int v = (i < N) ? counts[i] : 0;
    sh[tid] = v;
    __syncthreads();
    for (int off = 1; off < 1024; off <<= 1) {
        int t = (tid >= off) ? sh[tid - off] : 0;
        __syncthreads();
        sh[tid] += t;
        __syncthreads();
    }
    if (i < N) row_ptr[i] = sh[tid] - v;
    if (tid == 1023) partials[blockIdx.x] = sh[tid];
}

__global__ void scan2_kernel(int* partials, int nb) {
    if (threadIdx.x == 0 && blockIdx.x == 0) {
        int run = 0;
        for (int i = 0; i < nb; ++i) { int v = partials[i]; partials[i] = run; run += v; }
    }
}

__global__ void scan3_kernel(int* __restrict__ row_ptr, const int* __restrict__ partials,
                             int N, int E) {
    int i = blockIdx.x * 1024 + threadIdx.x;
    if (i < N) row_ptr[i] += partials[blockIdx.x];
    if (i == 0) row_ptr[N] = E;
}

__global__ __launch_bounds__(256) void partition_kernel(
        const int* __restrict__ src, const int* __restrict__ dst,
        const unsigned short* __restrict__ rank, const int* __restrict__ row_ptr,
        int* __restrict__ bucket_cursor, unsigned* __restrict__ staged, int E) {
    __shared__ unsigned pos_s[4096];
    __shared__ unsigned stage[4096];
    __shared__ unsigned char bkt_s[4096];
    __shared__ unsigned hist[256];
    __shared__ unsigned scanb[256];
    __shared__ unsigned baseg[256];
    __shared__ unsigned cnt[256];
    int tid = threadIdx.x;
    int e0 = blockIdx.x * 4096;
    hist[tid] = 0;
    cnt[tid] = 0;
    __syncthreads();
#pragma unroll
    for (int k = 0; k < 16; ++k) {
        int idx = k * 256 + tid;
        int i = e0 + idx;
        unsigned p = 0u;
        if (i < E) {
            int d = dst[i];
            p = (unsigned)(row_ptr[d] + (int)rank[i]);
            atomicAdd(&hist[p >> BKT_SHIFT], 1u);
        }
        pos_s[idx] = p;
    }
    __syncthreads();
    unsigned v = hist[tid];
    scanb[tid] = v;
    __syncthreads();
    for (int off = 1; off < 256; off <<= 1) {
        unsigned t = (tid >= off) ? scanb[tid - off] : 0;
        __syncthreads();
        scanb[tid] += t;
        __syncthreads();
    }
    unsigned excl = scanb[tid] - v;
    __syncthreads();
    scanb[tid] = excl;
    if (tid < NB)
        baseg[tid] = (unsigned)(tid * BKT_SIZE) + (unsigned)atomicAdd(&bucket_cursor[tid], (int)v);
    __syncthreads();
#pragma unroll
    for (int k = 0; k < 16; ++k) {
        int idx = k * 256 + tid;
        int i = e0 + idx;
        if (i < E) {
            unsigned p = pos_s[idx];
            unsigned b = p >> BKT_SHIFT;
            unsigned slot = scanb[b] + atomicAdd(&cnt[b], 1u);
            stage[slot] = ((p & (BKT_SIZE - 1)) << 17) | (unsigned)src[i];
            bkt_s[slot] = (unsigned char)b;
        }
    }
    __syncthreads();
    int total = min(4096, E - e0);
    for (int j = tid; j < total; j += 256) {
        unsigned b = bkt_s[j];
        unsigned addr = baseg[b] + ((unsigned)j - scanb[b]);
        staged[addr] = stage[j];
    }
}

__global__ __launch_bounds__(256) void bucket_kernel(const unsigned* __restrict__ staged,
                                                     int* __restrict__ csr_src, int E) {
    __shared__ int lsrc[BKT_SIZE];
    int base = blockIdx.x * BKT_SIZE;
    int count = min(BKT_SIZE, E - base);
    for (int j = threadIdx.x; j < count; j += 256) {
        unsigned pl = staged[base + j];
        lsrc[pl >> 17] = (int)(pl & 0x1FFFFu);
    }
    __syncthreads();
    const int4* ls4 = reinterpret_cast<const int4*>(lsrc);
    int4* out4 = reinterpret_cast<int4*>(csr_src + base);
    int c4 = count >> 2;
    for (int j = threadIdx.x; j < c4; j += 256) out4[j] = ls4[j];
    for (int j = (c4 << 2) + threadIdx.x; j < count; j += 256) csr_src[base + j] = lsrc[j];
}

// ---------------- W pre-transpose + bf16 hi/lo split: WT[n][k] ----------------
__global__ void wconv_kernel(const float* __restrict__ W, int K, int Nw, int Npad,
                             unsigned short* __restrict__ WTh, unsigned short* __restrict__ WTl) {
    int idx = blockIdx.x * 256 + threadIdx.x;
    if (idx >= Npad * K) return;
    int n = idx / K, k = idx % K;
    float x = (n < Nw) ? W[(size_t)k * Nw + n] : 0.f;
    short h, l;
    bfsplit(x, h, l);
    WTh[idx] = (unsigned short)h;
    WTl[idx] = (unsigned short)l;
}

// ---------------- MFMA GEMM (split-precision bf16) + el/er epilogue + bf16 feat ----------------
// Wave = 16 rows x full padded-N. A[m=lane&15][k=quad*8+j]; B[n=lane&15][k=quad*8+j];
// C/D: col=lane&15, row=quad*4+reg. 3 MFMAs per (nt,kt): Ah*Bh + Ah*Bl + Al*Bh.
template <int DIN, int NOUT, int NTILES, int OSTR>
__global__ __launch_bounds__(256) void gemm_mfma_kernel(
        const float* __restrict__ X,
        const unsigned short* __restrict__ WTh, const unsigned short* __restrict__ WTl,
        const float* __restrict__ al, const float* __restrict__ ar,
        unsigned short* __restrict__ featb, float* __restrict__ el,
        float* __restrict__ er, int N) {
    constexpr int KT = DIN / 32;
    using frag = __attribute__((ext_vector_type(8))) short;
    using accv = __attribute__((ext_vector_type(4))) float;

    int lane = threadIdx.x & 63;
    int wid = threadIdx.x >> 6;
    int r0 = (blockIdx.x * 4 + wid) * 16;
    if (r0 >= N) return;
    int m = lane & 15;
    int quad = lane >> 4;
    int row = r0 + m;
    bool rok = row < N;
    const float* xrow = X + (size_t)(rok ? row : 0) * DIN;

    frag ah[KT], alo[KT];
#pragma unroll
    for (int kt = 0; kt < KT; ++kt) {
        float xv[8];
        if (rok) {
            float4 a0 = *reinterpret_cast<const float4*>(xrow + kt * 32 + quad * 8);
            float4 a1 = *reinterpret_cast<const float4*>(xrow + kt * 32 + quad * 8 + 4);
            xv[0] = a0.x; xv[1] = a0.y; xv[2] = a0.z; xv[3] = a0.w;
            xv[4] = a1.x; xv[5] = a1.y; xv[6] = a1.z; xv[7] = a1.w;
        } else {
#pragma unroll
            for (int j = 0; j < 8; ++j) xv[j] = 0.f;
        }
#pragma unroll
        for (int j = 0; j < 8; ++j) {
            short h, l;
            bfsplit(xv[j], h, l);
            ah[kt][j] = h;
            alo[kt][j] = l;
        }
    }

    accv acc[NTILES];
#pragma unroll
    for (int nt = 0; nt < NTILES; ++nt) acc[nt] = (accv){0.f, 0.f, 0.f, 0.f};

#pragma unroll
    for (int nt = 0; nt < NTILES; ++nt) {
        const unsigned short* bh_base = WTh + (size_t)(nt * 16 + m) * DIN;
        const unsigned short* bl_base = WTl + (size_t)(nt * 16 + m) * DIN;
#pragma unroll
        for (int kt = 0; kt < KT; ++kt) {
            frag bh = *reinterpret_cast<const frag*>(bh_base + kt * 32 + quad * 8);
            frag bl = *reinterpret_cast<const frag*>(bl_base + kt * 32 + quad * 8);
            acc[nt] = __builtin_amdgcn_mfma_f32_16x16x32_bf16(ah[kt], bh, acc[nt], 0, 0, 0);
            acc[nt] = __builtin_amdgcn_mfma_f32_16x16x32_bf16(ah[kt], bl, acc[nt], 0, 0, 0);
            acc[nt] = __builtin_amdgcn_mfma_f32_16x16x32_bf16(alo[kt], bh, acc[nt], 0, 0, 0);
        }
    }

    // epilogue: bf16 feat store + el/er partials
    float pel[4] = {0.f, 0.f, 0.f, 0.f};
    float per[4] = {0.f, 0.f, 0.f, 0.f};
#pragma unroll
    for (int nt = 0; nt < NTILES; ++nt) {
        int n = nt * 16 + m;
        float av = (n < NOUT) ? al[n] : 0.f;
        float rv = (n < NOUT) ? ar[n] : 0.f;
#pragma unroll
        for (int reg = 0; reg < 4; ++reg) {
            float v = acc[nt][reg];
            pel[reg] += v * av;
            per[reg] += v * rv;
            int grow = r0 + quad * 4 + reg;
            if (grow < N && n < NOUT) {
                unsigned u = __float_as_uint(v);
                u = (u + 0x7fffu + ((u >> 16) & 1u)) >> 16;
                featb[(size_t)grow * OSTR + n] = (unsigned short)u;
            }
        }
    }
#pragma unroll
    for (int o = 1; o < 16; o <<= 1) {
#pragma unroll
        for (int reg = 0; reg < 4; ++reg) {
            pel[reg] += __shfl_xor(pel[reg], o, 64);
            per[reg] += __shfl_xor(per[reg], o, 64);
        }
    }
    if (m == 0) {
#pragma unroll
        for (int reg = 0; reg < 4; ++reg) {
            int grow = r0 + quad * 4 + reg;
            if (grow < N) { el[grow] = pel[reg]; er[grow] = per[reg]; }
        }
    }
}

// ---------------- Segment softmax + aggregation (bf16 gather, fp32 math) ----------------
template <int DOUT, int FSTR, int OSTR, bool ELU>
__global__ void agg_kernel(const int* __restrict__ row_ptr, const int* __restrict__ csr_src,
                           const float* __restrict__ el, const float* __restrict__ er,
                           const unsigned short* __restrict__ featb,
                           const float* __restrict__ bias, float* __restrict__ outp, int N) {
    int lane = threadIdx.x & 63;
    int n = blockIdx.x * (blockDim.x >> 6) + (threadIdx.x >> 6);
    if (n >= N) return;
    int beg = row_ptr[n];
    int end = row_ptr[n + 1];
    int deg = end - beg;
    float ern = er[n];

    constexpr int G2 = DOUT / 4;  // uint2 (4 bf16) chunks per row

    if (deg <= 64) {
        int s = 0;
        float e = -1e30f;
        bool act = lane < deg;
        if (act) {
            s = csr_src[beg + lane];
            e = leaky(el[s] + ern);
        }
        float m = e;
#pragma unroll
        for (int o = 32; o > 0; o >>= 1) m = fmaxf(m, __shfl_xor(m, o, 64));
        float ee = act ? __expf(e - m) : 0.f;
        float ssum = ee;
#pragma unroll
        for (int o = 32; o > 0; o >>= 1) ssum += __shfl_xor(ssum, o, 64);

        int g = lane >> 4;
        int cl = lane & 15;
        float4 acc = make_float4(0.f, 0.f, 0.f, 0.f);
        int niter = (deg + 3) >> 2;
        for (int i = 0; i < niter; i += 2) {
            int e0 = 4 * i + g;
            int e1 = e0 + 4;
            float w0 = __shfl(ee, e0 & 63, 64);
            int s0 = __shfl(s, e0 & 63, 64);
            float w1 = __shfl(ee, e1 & 63, 64);
            int s1 = __shfl(s, e1 & 63, 64);
            if (e0 >= deg) w0 = 0.f;
            if (e1 >= deg) w1 = 0.f;
            if (cl < G2) {
                uint2 q0 = *(reinterpret_cast<const uint2*>(featb + (size_t)s0 * FSTR) + cl);
                uint2 q1 = *(reinterpret_cast<const uint2*>(featb + (size_t)s1 * FSTR) + cl);
                acc.x += w0 * bflo(q0.x) + w1 * bflo(q1.x);
                acc.y += w0 * bfhi(q0.x) + w1 * bfhi(q1.x);
                acc.z += w0 * bflo(q0.y) + w1 * bflo(q1.y);
                acc.w += w0 * bfhi(q0.y) + w1 * bfhi(q1.y);
            }
        }
#pragma unroll
        for (int o = 16; o <= 32; o <<= 1) {
            acc.x += __shfl_xor(acc.x, o, 64);
            acc.y += __shfl_xor(acc.y, o, 64);
            acc.z += __shfl_xor(acc.z, o, 64);
            acc.w += __shfl_xor(acc.w, o, 64);
        }
        if (g == 0 && cl < G2) {
            float inv = (deg > 0) ? 1.f / ssum : 0.f;
            const float4 b4 = reinterpret_cast<const float4*>(bias)[cl];
            float4 o4;
            o4.x = acc.x * inv + b4.x;
            o4.y = acc.y * inv + b4.y;
            o4.z = acc.z * inv + b4.z;
            o4.w = acc.w * inv + b4.w;
            if (ELU) {
                o4.x = o4.x > 0.f ? o4.x : (__expf(o4.x) - 1.f);
                o4.y = o4.y > 0.f ? o4.y : (__expf(o4.y) - 1.f);
                o4.z = o4.z > 0.f ? o4.z : (__expf(o4.z) - 1.f);
                o4.w = o4.w > 0.f ? o4.w : (__expf(o4.w) - 1.f);
            }
            *reinterpret_cast<float4*>(outp + (size_t)n * OSTR + 4 * cl) = o4;
        }
        return;
    }

    // slow path (deg > 64)
    float m = -1e30f;
    for (int j = beg + lane; j < end; j += 64) {
        float e = leaky(el[csr_src[j]] + ern);
        m = fmaxf(m, e);
    }
#pragma unroll
    for (int o = 32; o > 0; o >>= 1) m = fmaxf(m, __shfl_xor(m, o, 64));

    float ssum = 0.f;
    float acc = 0.f;
    for (int base = beg; base < end; base += 64) {
        int j = base + lane;
        int cnt = min(64, end - base);
        int s = (lane < cnt) ? csr_src[j] : 0;
        float ee = 0.f;
        if (lane < cnt) {
            float e = leaky(el[s] + ern);
            ee = __expf(e - m);
        }
        ssum += ee;
        for (int t = 0; t < cnt; ++t) {
            float w = __shfl(ee, t, 64);
            int sj = __shfl(s, t, 64);
            if (lane < DOUT)
                acc += w * __uint_as_float(((unsigned)featb[(size_t)sj * FSTR + lane]) << 16);
        }
    }
#pragma unroll
    for (int o = 32; o > 0; o >>= 1) ssum += __shfl_xor(ssum, o, 64);

    if (lane < DOUT) {
        float o = acc / ssum + bias[lane];
        if (ELU) o = (o > 0.f) ? o : (__expf(o) - 1.f);
        outp[(size_t)n * OSTR + lane] = o;
    }
}

extern "C" void kernel_launch(void* const* d_in, const int* in_sizes, int n_in,
                              void* d_out, int out_size, void* d_ws, size_t ws_size,
                              hipStream_t stream) {
    const float* in_feat = (const float*)d_in[0];
    const int* src = (const int*)d_in[1];
    const int* dst = (const int*)d_in[2];
    const float* W1 = (const float*)d_in[3];
    const float* al1 = (const float*)d_in[4];
    const float* ar1 = (const float*)d_in[5];
    const float* b1 = (const float*)d_in[6];
    const float* W2 = (const float*)d_in[7];
    const float* al2 = (const float*)d_in[8];
    const float* ar2 = (const float*)d_in[9];
    const float* b2 = (const float*)d_in[10];
    float* out = (float*)d_out;

    const int N = N_NODES, E = N_EDGES;
    const int E_PAD = NB * BKT_SIZE;

    size_t off = 0;
    auto carve = [&](size_t bytes) {
        void* p = (char*)d_ws + off;
        off += (bytes + 255) & ~(size_t)255;
        return p;
    };
    // long-lived
    unsigned short* featb = (unsigned short*)carve((size_t)N * 64 * 2);  // bf16 gather table
    float* el    = (float*)carve((size_t)N * 4);
    float* er    = (float*)carve((size_t)N * 4);
    int* row_ptr = (int*)carve((size_t)(N + 1) * 4);
    int* csr_src = (int*)carve((size_t)E * 4);
    int* bucket_cursor = (int*)carve((size_t)NB * 4);
    unsigned short* W1Th = (unsigned short*)carve((size_t)64 * 128 * 2);
    unsigned short* W1Tl = (unsigned short*)carve((size_t)64 * 128 * 2);
    unsigned short* W2Th = (unsigned short*)carve((size_t)48 * 64 * 2);
    unsigned short* W2Tl = (unsigned short*)carve((size_t)48 * 64 * 2);
    // h overlaps the CSR-build temporaries (all dead before agg1 writes h)
    size_t offH = off;
    float* h = (float*)carve((size_t)N * 64 * 4);
    size_t off_end = off;
    off = offH;
    unsigned short* rank = (unsigned short*)carve((size_t)E * 2);
    unsigned* staged     = (unsigned*)carve((size_t)E_PAD * 4);
    int* counts          = (int*)carve((size_t)N * 4);
    int* partials        = (int*)carve(1024 * 4);
    off = off_end;

    hipMemsetAsync(counts, 0, (size_t)N * 4, stream);
    hipMemsetAsync(bucket_cursor, 0, (size_t)NB * 4, stream);

    int egrid = (E + 255) / 256;
    count_rank_kernel<<<egrid, 256, 0, stream>>>(dst, counts, rank, E);
    int nb = (N + 1023) / 1024;
    scan1_kernel<<<nb, 1024, 0, stream>>>(counts, row_ptr, partials, N);
    scan2_kernel<<<1, 64, 0, stream>>>(partials, nb);
    scan3_kernel<<<nb, 1024, 0, stream>>>(row_ptr, partials, N, E);
    int pgrid = (E + 4095) / 4096;
    partition_kernel<<<pgrid, 256, 0, stream>>>(src, dst, rank, row_ptr, bucket_cursor, staged, E);
    bucket_kernel<<<NB, 256, 0, stream>>>(staged, csr_src, E);

    // W pre-transpose/split (tiny)
    wconv_kernel<<<(64 * 128 + 255) / 256, 256, 0, stream>>>(W1, 128, 64, 64, W1Th, W1Tl);
    wconv_kernel<<<(48 * 64 + 255) / 256, 256, 0, stream>>>(W2, 64, 40, 48, W2Th, W2Tl);

    int agrid = (N + 3) / 4;
    int ggrid = (N + 63) / 64;

    // layer 1: MFMA GEMM 100K x 128 -> 64
    gemm_mfma_kernel<128, 64, 4, 64>
        <<<ggrid, 256, 0, stream>>>(in_feat, W1Th, W1Tl, al1, ar1, featb, el, er, N);
    agg_kernel<64, 64, 64, true><<<agrid, 256, 0, stream>>>(row_ptr, csr_src, el, er, featb, b1, h, N);

    // layer 2: MFMA GEMM 100K x 64 -> 40 (padded N=48; featb stride 48)
    gemm_mfma_kernel<64, 40, 3, 48>
        <<<ggrid, 256, 0, stream>>>(h, W2Th, W2Tl, al2, ar2, featb, el, er, N);
    agg_kernel<40, 48, 40, false><<<agrid, 256, 0, stream>>>(row_ptr, csr_src, el, er, featb, b2, out, N);
}

// Round 7
// 295.921 us; speedup vs baseline: 2.0632x; 1.2652x over previous
//
#include <hip/hip_runtime.h>

#define N_NODES 100000
#define N_EDGES 1600000
// dst-keyed two-level counting sort
#define DB_SHIFT 9
#define DB_SIZE 512
#define NDB 196      // ceil(N_NODES / 512)
#define DB_CAP 10240 // per-bucket capacity; mean 8163, std ~90 (seed fixed) -> 23 sigma

constexpr float NEG_SLOPE = 0.2f;

__device__ __forceinline__ float leaky(float x) { return x > 0.f ? x : NEG_SLOPE * x; }

__device__ __forceinline__ float bflo(unsigned u) { return __uint_as_float(u << 16); }
__device__ __forceinline__ float bfhi(unsigned u) { return __uint_as_float(u & 0xffff0000u); }

// split fp32 -> bf16 hi (truncate) + bf16 lo (RNE of residual); x ~= hi + lo with ~2^-16 rel err
__device__ __forceinline__ void bfsplit(float x, short& h, short& l) {
    unsigned u = __float_as_uint(x);
    h = (short)(u >> 16);
    float res = x - __uint_as_float(u & 0xffff0000u);
    unsigned r = __float_as_uint(res);
    r = (r + 0x7fffu + ((r >> 16) & 1u)) >> 16;
    l = (short)r;
}

// ---------------- CSR build: partition by dst>>9, then per-bucket LDS counting sort ----------------
__global__ __launch_bounds__(256) void partition_dst_kernel(
        const int* __restrict__ src, const int* __restrict__ dst,
        int* __restrict__ db_cursor, unsigned* __restrict__ staged, int E) {
    __shared__ unsigned pay_s[4096];
    __shared__ unsigned stage[4096];
    __shared__ unsigned char bktA[4096];
    __shared__ unsigned char bkt_s[4096];
    __shared__ unsigned hist[256];
    __shared__ unsigned scanb[256];
    __shared__ unsigned baseg[256];
    __shared__ unsigned cnt[256];
    int tid = threadIdx.x;
    int e0 = blockIdx.x * 4096;
    hist[tid] = 0;
    cnt[tid] = 0;
    __syncthreads();
#pragma unroll
    for (int k = 0; k < 16; ++k) {
        int idx = k * 256 + tid;
        int i = e0 + idx;
        if (i < E) {
            int d = dst[i];
            unsigned b = (unsigned)d >> DB_SHIFT;
            pay_s[idx] = (((unsigned)d & (DB_SIZE - 1)) << 17) | (unsigned)src[i];
            bktA[idx] = (unsigned char)b;
            atomicAdd(&hist[b], 1u);
        }
    }
    __syncthreads();
    unsigned v = hist[tid];
    scanb[tid] = v;
    __syncthreads();
    for (int off = 1; off < 256; off <<= 1) {
        unsigned t = (tid >= off) ? scanb[tid - off] : 0;
        __syncthreads();
        scanb[tid] += t;
        __syncthreads();
    }
    unsigned excl = scanb[tid] - v;
    __syncthreads();
    scanb[tid] = excl;
    if (tid < NDB)
        baseg[tid] = (unsigned)(tid * DB_CAP) + (unsigned)atomicAdd(&db_cursor[tid], (int)v);
    __syncthreads();
#pragma unroll
    for (int k = 0; k < 16; ++k) {
        int idx = k * 256 + tid;
        int i = e0 + idx;
        if (i < E) {
            unsigned b = bktA[idx];
            unsigned slot = scanb[b] + atomicAdd(&cnt[b], 1u);
            stage[slot] = pay_s[idx];
            bkt_s[slot] = (unsigned char)b;
        }
    }
    __syncthreads();
    int total = min(4096, E - e0);
    for (int j = tid; j < total; j += 256) {
        unsigned b = bkt_s[j];
        unsigned addr = baseg[b] + ((unsigned)j - scanb[b]);
        staged[addr] = stage[j];
    }
}

// exclusive scan of the 196 bucket counts (single block)
__global__ __launch_bounds__(256) void bucket_scan_kernel(const int* __restrict__ db_cursor,
                                                          int* __restrict__ db_base,
                                                          int* __restrict__ row_ptr, int N, int E) {
    __shared__ int sh[256];
    int tid = threadIdx.x;
    int c = (tid < NDB) ? db_cursor[tid] : 0;
    sh[tid] = c;
    __syncthreads();
    for (int off = 1; off < 256; off <<= 1) {
        int t = (tid >= off) ? sh[tid - off] : 0;
        __syncthreads();
        sh[tid] += t;
        __syncthreads();
    }
    if (tid < NDB) db_base[tid] = sh[tid] - c;
    if (tid == 0) row_ptr[N] = E;
}

// one block per bucket: LDS counting sort of <=DB_CAP edges over 512 local dst nodes
__global__ __launch_bounds__(256) void bucket_sort_kernel(
        const unsigned* __restrict__ staged, const int* __restrict__ db_cnt,
        const int* __restrict__ db_base, int* __restrict__ csr_src,
        int* __restrict__ row_ptr, int N) {
    __shared__ unsigned pay[DB_CAP];
    __shared__ int sorted[DB_CAP];
    __shared__ int hist[DB_SIZE];
    __shared__ int excl[DB_SIZE];
    __shared__ int psum[256];
    int tid = threadIdx.x;
    int k = blockIdx.x;
    int cnt = db_cnt[k];
    int base = db_base[k];
    for (int i = tid; i < DB_SIZE; i += 256) hist[i] = 0;
    __syncthreads();
    for (int j = tid; j < cnt; j += 256) {
        unsigned p = staged[(size_t)k * DB_CAP + j];
        pay[j] = p;
        atomicAdd(&hist[p >> 17], 1);
    }
    __syncthreads();
    // exclusive scan of 512 via 256-thread pair scan
    int s = hist[2 * tid] + hist[2 * tid + 1];
    psum[tid] = s;
    __syncthreads();
    for (int off = 1; off < 256; off <<= 1) {
        int t = (tid >= off) ? psum[tid - off] : 0;
        __syncthreads();
        psum[tid] += t;
        __syncthreads();
    }
    int e0 = psum[tid] - s;
    excl[2 * tid] = e0;
    excl[2 * tid + 1] = e0 + hist[2 * tid];
    __syncthreads();
    for (int i = tid; i < DB_SIZE; i += 256) {
        int d = k * DB_SIZE + i;
        if (d < N) row_ptr[d] = base + excl[i];
    }
    for (int i = tid; i < DB_SIZE; i += 256) hist[i] = 0;
    __syncthreads();
    for (int j = tid; j < cnt; j += 256) {
        unsigned p = pay[j];
        int dl = (int)(p >> 17);
        int pos = excl[dl] + atomicAdd(&hist[dl], 1);
        sorted[pos] = (int)(p & 0x1FFFFu);
    }
    __syncthreads();
    for (int j = tid; j < cnt; j += 256) csr_src[base + j] = sorted[j];
}

// ---------------- W pre-transpose + bf16 hi/lo split: WT[n][k] ----------------
__global__ void wconv_kernel(const float* __restrict__ W, int K, int Nw, int Npad,
                             unsigned short* __restrict__ WTh, unsigned short* __restrict__ WTl) {
    int idx = blockIdx.x * 256 + threadIdx.x;
    if (idx >= Npad * K) return;
    int n = idx / K, k = idx % K;
    float x = (n < Nw) ? W[(size_t)k * Nw + n] : 0.f;
    short h, l;
    bfsplit(x, h, l);
    WTh[idx] = (unsigned short)h;
    WTl[idx] = (unsigned short)l;
}

// ---------------- MFMA GEMM (split-precision bf16) + el/er epilogue + bf16 feat ----------------
template <int DIN, int NOUT, int NTILES, int OSTR>
__global__ __launch_bounds__(256) void gemm_mfma_kernel(
        const float* __restrict__ X,
        const unsigned short* __restrict__ WTh, const unsigned short* __restrict__ WTl,
        const float* __restrict__ al, const float* __restrict__ ar,
        unsigned short* __restrict__ featb, float* __restrict__ el,
        float* __restrict__ er, int N) {
    constexpr int KT = DIN / 32;
    using frag = __attribute__((ext_vector_type(8))) short;
    using accv = __attribute__((ext_vector_type(4))) float;

    int lane = threadIdx.x & 63;
    int wid = threadIdx.x >> 6;
    int r0 = (blockIdx.x * 4 + wid) * 16;
    if (r0 >= N) return;
    int m = lane & 15;
    int quad = lane >> 4;
    int row = r0 + m;
    bool rok = row < N;
    const float* xrow = X + (size_t)(rok ? row : 0) * DIN;

    frag ah[KT], alo[KT];
#pragma unroll
    for (int kt = 0; kt < KT; ++kt) {
        float xv[8];
        if (rok) {
            float4 a0 = *reinterpret_cast<const float4*>(xrow + kt * 32 + quad * 8);
            float4 a1 = *reinterpret_cast<const float4*>(xrow + kt * 32 + quad * 8 + 4);
            xv[0] = a0.x; xv[1] = a0.y; xv[2] = a0.z; xv[3] = a0.w;
            xv[4] = a1.x; xv[5] = a1.y; xv[6] = a1.z; xv[7] = a1.w;
        } else {
#pragma unroll
            for (int j = 0; j < 8; ++j) xv[j] = 0.f;
        }
#pragma unroll
        for (int j = 0; j < 8; ++j) {
            short h, l;
            bfsplit(xv[j], h, l);
            ah[kt][j] = h;
            alo[kt][j] = l;
        }
    }

    accv acc[NTILES];
#pragma unroll
    for (int nt = 0; nt < NTILES; ++nt) acc[nt] = (accv){0.f, 0.f, 0.f, 0.f};

#pragma unroll
    for (int nt = 0; nt < NTILES; ++nt) {
        const unsigned short* bh_base = WTh + (size_t)(nt * 16 + m) * DIN;
        const unsigned short* bl_base = WTl + (size_t)(nt * 16 + m) * DIN;
#pragma unroll
        for (int kt = 0; kt < KT; ++kt) {
            frag bh = *reinterpret_cast<const frag*>(bh_base + kt * 32 + quad * 8);
            frag bl = *reinterpret_cast<const frag*>(bl_base + kt * 32 + quad * 8);
            acc[nt] = __builtin_amdgcn_mfma_f32_16x16x32_bf16(ah[kt], bh, acc[nt], 0, 0, 0);
            acc[nt] = __builtin_amdgcn_mfma_f32_16x16x32_bf16(ah[kt], bl, acc[nt], 0, 0, 0);
            acc[nt] = __builtin_amdgcn_mfma_f32_16x16x32_bf16(alo[kt], bh, acc[nt], 0, 0, 0);
        }
    }

    float pel[4] = {0.f, 0.f, 0.f, 0.f};
    float per[4] = {0.f, 0.f, 0.f, 0.f};
#pragma unroll
    for (int nt = 0; nt < NTILES; ++nt) {
        int n = nt * 16 + m;
        float av = (n < NOUT) ? al[n] : 0.f;
        float rv = (n < NOUT) ? ar[n] : 0.f;
#pragma unroll
        for (int reg = 0; reg < 4; ++reg) {
            float v = acc[nt][reg];
            pel[reg] += v * av;
            per[reg] += v * rv;
            int grow = r0 + quad * 4 + reg;
            if (grow < N && n < NOUT) {
                unsigned u = __float_as_uint(v);
                u = (u + 0x7fffu + ((u >> 16) & 1u)) >> 16;
                featb[(size_t)grow * OSTR + n] = (unsigned short)u;
            }
        }
    }
#pragma unroll
    for (int o = 1; o < 16; o <<= 1) {
#pragma unroll
        for (int reg = 0; reg < 4; ++reg) {
            pel[reg] += __shfl_xor(pel[reg], o, 64);
            per[reg] += __shfl_xor(per[reg], o, 64);
        }
    }
    if (m == 0) {
#pragma unroll
        for (int reg = 0; reg < 4; ++reg) {
            int grow = r0 + quad * 4 + reg;
            if (grow < N) { el[grow] = pel[reg]; er[grow] = per[reg]; }
        }
    }
}

// ---------------- Segment softmax + aggregation (bf16 gather, fp32 math) ----------------
template <int DOUT, int FSTR, int OSTR, bool ELU>
__global__ void agg_kernel(const int* __restrict__ row_ptr, const int* __restrict__ csr_src,
                           const float* __restrict__ el, const float* __restrict__ er,
                           const unsigned short* __restrict__ featb,
                           const float* __restrict__ bias, float* __restrict__ outp, int N) {
    int lane = threadIdx.x & 63;
    int n = blockIdx.x * (blockDim.x >> 6) + (threadIdx.x >> 6);
    if (n >= N) return;
    int beg = row_ptr[n];
    int end = row_ptr[n + 1];
    int deg = end - beg;
    float ern = er[n];

    constexpr int G2 = DOUT / 4;

    if (deg <= 64) {
        int s = 0;
        float e = -1e30f;
        bool act = lane < deg;
        if (act) {
            s = csr_src[beg + lane];
            e = leaky(el[s] + ern);
        }
        float m = e;
#pragma unroll
        for (int o = 32; o > 0; o >>= 1) m = fmaxf(m, __shfl_xor(m, o, 64));
        float ee = act ? __expf(e - m) : 0.f;
        float ssum = ee;
#pragma unroll
        for (int o = 32; o > 0; o >>= 1) ssum += __shfl_xor(ssum, o, 64);

        int g = lane >> 4;
        int cl = lane & 15;
        float4 acc = make_float4(0.f, 0.f, 0.f, 0.f);
        int niter = (deg + 3) >> 2;
        for (int i = 0; i < niter; i += 2) {
            int e0 = 4 * i + g;
            int e1 = e0 + 4;
            float w0 = __shfl(ee, e0 & 63, 64);
            int s0 = __shfl(s, e0 & 63, 64);
            float w1 = __shfl(ee, e1 & 63, 64);
            int s1 = __shfl(s, e1 & 63, 64);
            if (e0 >= deg) w0 = 0.f;
            if (e1 >= deg) w1 = 0.f;
            if (cl < G2) {
                uint2 q0 = *(reinterpret_cast<const uint2*>(featb + (size_t)s0 * FSTR) + cl);
                uint2 q1 = *(reinterpret_cast<const uint2*>(featb + (size_t)s1 * FSTR) + cl);
                acc.x += w0 * bflo(q0.x) + w1 * bflo(q1.x);
                acc.y += w0 * bfhi(q0.x) + w1 * bfhi(q1.x);
                acc.z += w0 * bflo(q0.y) + w1 * bflo(q1.y);
                acc.w += w0 * bfhi(q0.y) + w1 * bfhi(q1.y);
            }
        }
#pragma unroll
        for (int o = 16; o <= 32; o <<= 1) {
            acc.x += __shfl_xor(acc.x, o, 64);
            acc.y += __shfl_xor(acc.y, o, 64);
            acc.z += __shfl_xor(acc.z, o, 64);
            acc.w += __shfl_xor(acc.w, o, 64);
        }
        if (g == 0 && cl < G2) {
            float inv = (deg > 0) ? 1.f / ssum : 0.f;
            const float4 b4 = reinterpret_cast<const float4*>(bias)[cl];
            float4 o4;
            o4.x = acc.x * inv + b4.x;
            o4.y = acc.y * inv + b4.y;
            o4.z = acc.z * inv + b4.z;
            o4.w = acc.w * inv + b4.w;
            if (ELU) {
                o4.x = o4.x > 0.f ? o4.x : (__expf(o4.x) - 1.f);
                o4.y = o4.y > 0.f ? o4.y : (__expf(o4.y) - 1.f);
                o4.z = o4.z > 0.f ? o4.z : (__expf(o4.z) - 1.f);
                o4.w = o4.w > 0.f ? o4.w : (__expf(o4.w) - 1.f);
            }
            *reinterpret_cast<float4*>(outp + (size_t)n * OSTR + 4 * cl) = o4;
        }
        return;
    }

    // slow path (deg > 64)
    float m = -1e30f;
    for (int j = beg + lane; j < end; j += 64) {
        float e = leaky(el[csr_src[j]] + ern);
        m = fmaxf(m, e);
    }
#pragma unroll
    for (int o = 32; o > 0; o >>= 1) m = fmaxf(m, __shfl_xor(m, o, 64));

    float ssum = 0.f;
    float acc = 0.f;
    for (int base = beg; base < end; base += 64) {
        int j = base + lane;
        int cnt = min(64, end - base);
        int s = (lane < cnt) ? csr_src[j] : 0;
        float ee = 0.f;
        if (lane < cnt) {
            float e = leaky(el[s] + ern);
            ee = __expf(e - m);
        }
        ssum += ee;
        for (int t = 0; t < cnt; ++t) {
            float w = __shfl(ee, t, 64);
            int sj = __shfl(s, t, 64);
            if (lane < DOUT)
                acc += w * __uint_as_float(((unsigned)featb[(size_t)sj * FSTR + lane]) << 16);
        }
    }
#pragma unroll
    for (int o = 32; o > 0; o >>= 1) ssum += __shfl_xor(ssum, o, 64);

    if (lane < DOUT) {
        float o = acc / ssum + bias[lane];
        if (ELU) o = (o > 0.f) ? o : (__expf(o) - 1.f);
        outp[(size_t)n * OSTR + lane] = o;
    }
}

extern "C" void kernel_launch(void* const* d_in, const int* in_sizes, int n_in,
                              void* d_out, int out_size, void* d_ws, size_t ws_size,
                              hipStream_t stream) {
    const float* in_feat = (const float*)d_in[0];
    const int* src = (const int*)d_in[1];
    const int* dst = (const int*)d_in[2];
    const float* W1 = (const float*)d_in[3];
    const float* al1 = (const float*)d_in[4];
    const float* ar1 = (const float*)d_in[5];
    const float* b1 = (const float*)d_in[6];
    const float* W2 = (const float*)d_in[7];
    const float* al2 = (const float*)d_in[8];
    const float* ar2 = (const float*)d_in[9];
    const float* b2 = (const float*)d_in[10];
    float* out = (float*)d_out;

    const int N = N_NODES, E = N_EDGES;

    size_t off = 0;
    auto carve = [&](size_t bytes) {
        void* p = (char*)d_ws + off;
        off += (bytes + 255) & ~(size_t)255;
        return p;
    };
    // long-lived
    unsigned short* featb = (unsigned short*)carve((size_t)N * 64 * 2);  // bf16 gather table
    float* el    = (float*)carve((size_t)N * 4);
    float* er    = (float*)carve((size_t)N * 4);
    int* row_ptr = (int*)carve((size_t)(N + 1) * 4);
    int* csr_src = (int*)carve((size_t)E * 4);
    int* db_cursor = (int*)carve((size_t)NDB * 4);
    int* db_base   = (int*)carve((size_t)NDB * 4);
    unsigned short* W1Th = (unsigned short*)carve((size_t)64 * 128 * 2);
    unsigned short* W1Tl = (unsigned short*)carve((size_t)64 * 128 * 2);
    unsigned short* W2Th = (unsigned short*)carve((size_t)48 * 64 * 2);
    unsigned short* W2Tl = (unsigned short*)carve((size_t)48 * 64 * 2);
    // h overlaps staged (staged dead before agg1 writes h)
    size_t offH = off;
    float* h = (float*)carve((size_t)N * 64 * 4);
    size_t off_end = off;
    off = offH;
    unsigned* staged = (unsigned*)carve((size_t)NDB * DB_CAP * 4);  // 8.0 MB < 25.6 MB
    off = off_end;

    hipMemsetAsync(db_cursor, 0, (size_t)NDB * 4, stream);

    // CSR build: 3 kernels, no global atomic histograms
    partition_dst_kernel<<<(E + 4095) / 4096, 256, 0, stream>>>(src, dst, db_cursor, staged, E);
    bucket_scan_kernel<<<1, 256, 0, stream>>>(db_cursor, db_base, row_ptr, N, E);
    bucket_sort_kernel<<<NDB, 256, 0, stream>>>(staged, db_cursor, db_base, csr_src, row_ptr, N);

    // W pre-transpose/split (tiny)
    wconv_kernel<<<(64 * 128 + 255) / 256, 256, 0, stream>>>(W1, 128, 64, 64, W1Th, W1Tl);
    wconv_kernel<<<(48 * 64 + 255) / 256, 256, 0, stream>>>(W2, 64, 40, 48, W2Th, W2Tl);

    int agrid = (N + 3) / 4;
    int ggrid = (N + 63) / 64;

    // layer 1: MFMA GEMM 100K x 128 -> 64
    gemm_mfma_kernel<128, 64, 4, 64>
        <<<ggrid, 256, 0, stream>>>(in_feat, W1Th, W1Tl, al1, ar1, featb, el, er, N);
    agg_kernel<64, 64, 64, true><<<agrid, 256, 0, stream>>>(row_ptr, csr_src, el, er, featb, b1, h, N);

    // layer 2: MFMA GEMM 100K x 64 -> 40 (padded N=48; featb stride 48)
    gemm_mfma_kernel<64, 40, 3, 48>
        <<<ggrid, 256, 0, stream>>>(h, W2Th, W2Tl, al2, ar2, featb, el, er, N);
    agg_kernel<40, 48, 40, false><<<agrid, 256, 0, stream>>>(row_ptr, csr_src, el, er, featb, b2, out, N);
}

// Round 8
// 288.625 us; speedup vs baseline: 2.1154x; 1.0253x over previous
//
#include <hip/hip_runtime.h>

#define N_NODES 100000
#define N_EDGES 1600000
// dst-keyed two-level counting sort
#define DB_SHIFT 9
#define DB_SIZE 512
#define NDB 196      // ceil(N_NODES / 512)
#define DB_CAP 10240 // per-bucket capacity; mean 8163, std ~90 (seed fixed) -> 23 sigma
#define PART_EDGES 2048
#define NPART ((N_EDGES + PART_EDGES - 1) / PART_EDGES)  // 782
#define NGEMM1 ((N_NODES + 63) / 64)                     // 1563

constexpr float NEG_SLOPE = 0.2f;

__device__ __forceinline__ float leaky(float x) { return x > 0.f ? x : NEG_SLOPE * x; }

__device__ __forceinline__ float bflo(unsigned u) { return __uint_as_float(u << 16); }
__device__ __forceinline__ float bfhi(unsigned u) { return __uint_as_float(u & 0xffff0000u); }

// split fp32 -> bf16 hi (truncate) + bf16 lo (RNE of residual); x ~= hi + lo with ~2^-16 rel err
__device__ __forceinline__ void bfsplit(float x, short& h, short& l) {
    unsigned u = __float_as_uint(x);
    h = (short)(u >> 16);
    float res = x - __uint_as_float(u & 0xffff0000u);
    unsigned r = __float_as_uint(res);
    r = (r + 0x7fffu + ((r >> 16) & 1u)) >> 16;
    l = (short)r;
}

// ---------------- combined W transpose/split (W1 + W2) + db_cursor zeroing ----------------
__global__ void wconv2_kernel(const float* __restrict__ W1, const float* __restrict__ W2,
                              unsigned short* __restrict__ W1Th, unsigned short* __restrict__ W1Tl,
                              unsigned short* __restrict__ W2Th, unsigned short* __restrict__ W2Tl,
                              int* __restrict__ db_cursor) {
    int idx = blockIdx.x * 256 + threadIdx.x;
    if (blockIdx.x == 0 && threadIdx.x < NDB) db_cursor[threadIdx.x] = 0;
    if (idx < 64 * 128) {
        int n = idx / 128, k = idx % 128;
        short h, l;
        bfsplit(W1[(size_t)k * 64 + n], h, l);
        W1Th[idx] = (unsigned short)h;
        W1Tl[idx] = (unsigned short)l;
    } else if (idx < 64 * 128 + 48 * 64) {
        int j = idx - 64 * 128;
        int n = j / 64, k = j % 64;
        float x = (n < 40) ? W2[(size_t)k * 40 + n] : 0.f;
        short h, l;
        bfsplit(x, h, l);
        W2Th[j] = (unsigned short)h;
        W2Tl[j] = (unsigned short)l;
    }
}

// ---------------- MFMA GEMM body (shared by fusedA and gemm2) ----------------
template <int DIN, int NOUT, int NTILES, int OSTR>
__device__ __forceinline__ void gemm_mfma_body(
        int bid, const float* __restrict__ X,
        const unsigned short* __restrict__ WTh, const unsigned short* __restrict__ WTl,
        const float* __restrict__ al, const float* __restrict__ ar,
        unsigned short* __restrict__ featb, float* __restrict__ el,
        float* __restrict__ er, int N) {
    constexpr int KT = DIN / 32;
    using frag = __attribute__((ext_vector_type(8))) short;
    using accv = __attribute__((ext_vector_type(4))) float;

    int lane = threadIdx.x & 63;
    int wid = threadIdx.x >> 6;
    int r0 = (bid * 4 + wid) * 16;
    if (r0 >= N) return;
    int m = lane & 15;
    int quad = lane >> 4;
    int row = r0 + m;
    bool rok = row < N;
    const float* xrow = X + (size_t)(rok ? row : 0) * DIN;

    frag ah[KT], alo[KT];
#pragma unroll
    for (int kt = 0; kt < KT; ++kt) {
        float xv[8];
        if (rok) {
            float4 a0 = *reinterpret_cast<const float4*>(xrow + kt * 32 + quad * 8);
            float4 a1 = *reinterpret_cast<const float4*>(xrow + kt * 32 + quad * 8 + 4);
            xv[0] = a0.x; xv[1] = a0.y; xv[2] = a0.z; xv[3] = a0.w;
            xv[4] = a1.x; xv[5] = a1.y; xv[6] = a1.z; xv[7] = a1.w;
        } else {
#pragma unroll
            for (int j = 0; j < 8; ++j) xv[j] = 0.f;
        }
#pragma unroll
        for (int j = 0; j < 8; ++j) {
            short h, l;
            bfsplit(xv[j], h, l);
            ah[kt][j] = h;
            alo[kt][j] = l;
        }
    }

    accv acc[NTILES];
#pragma unroll
    for (int nt = 0; nt < NTILES; ++nt) acc[nt] = (accv){0.f, 0.f, 0.f, 0.f};

#pragma unroll
    for (int nt = 0; nt < NTILES; ++nt) {
        const unsigned short* bh_base = WTh + (size_t)(nt * 16 + m) * DIN;
        const unsigned short* bl_base = WTl + (size_t)(nt * 16 + m) * DIN;
#pragma unroll
        for (int kt = 0; kt < KT; ++kt) {
            frag bh = *reinterpret_cast<const frag*>(bh_base + kt * 32 + quad * 8);
            frag bl = *reinterpret_cast<const frag*>(bl_base + kt * 32 + quad * 8);
            acc[nt] = __builtin_amdgcn_mfma_f32_16x16x32_bf16(ah[kt], bh, acc[nt], 0, 0, 0);
            acc[nt] = __builtin_amdgcn_mfma_f32_16x16x32_bf16(ah[kt], bl, acc[nt], 0, 0, 0);
            acc[nt] = __builtin_amdgcn_mfma_f32_16x16x32_bf16(alo[kt], bh, acc[nt], 0, 0, 0);
        }
    }

    float pel[4] = {0.f, 0.f, 0.f, 0.f};
    float per[4] = {0.f, 0.f, 0.f, 0.f};
#pragma unroll
    for (int nt = 0; nt < NTILES; ++nt) {
        int n = nt * 16 + m;
        float av = (n < NOUT) ? al[n] : 0.f;
        float rv = (n < NOUT) ? ar[n] : 0.f;
#pragma unroll
        for (int reg = 0; reg < 4; ++reg) {
            float v = acc[nt][reg];
            pel[reg] += v * av;
            per[reg] += v * rv;
            int grow = r0 + quad * 4 + reg;
            if (grow < N && n < NOUT) {
                unsigned u = __float_as_uint(v);
                u = (u + 0x7fffu + ((u >> 16) & 1u)) >> 16;
                featb[(size_t)grow * OSTR + n] = (unsigned short)u;
            }
        }
    }
#pragma unroll
    for (int o = 1; o < 16; o <<= 1) {
#pragma unroll
        for (int reg = 0; reg < 4; ++reg) {
            pel[reg] += __shfl_xor(pel[reg], o, 64);
            per[reg] += __shfl_xor(per[reg], o, 64);
        }
    }
    if (m == 0) {
#pragma unroll
        for (int reg = 0; reg < 4; ++reg) {
            int grow = r0 + quad * 4 + reg;
            if (grow < N) { el[grow] = pel[reg]; er[grow] = per[reg]; }
        }
    }
}

// ---------------- fusedA: partition_dst (blocks [0,NPART)) + gemm1 (rest) ----------------
__global__ __launch_bounds__(256) void fusedA_kernel(
        const int* __restrict__ src, const int* __restrict__ dst,
        int* __restrict__ db_cursor, unsigned* __restrict__ staged, int E,
        const float* __restrict__ X,
        const unsigned short* __restrict__ W1Th, const unsigned short* __restrict__ W1Tl,
        const float* __restrict__ al, const float* __restrict__ ar,
        unsigned short* __restrict__ featb, float* __restrict__ el,
        float* __restrict__ er, int N) {
    if (blockIdx.x < NPART) {
        // -------- partition by dst>>9; 2048 edges per block --------
        __shared__ unsigned pay_s[PART_EDGES];
        __shared__ unsigned stage[PART_EDGES];
        __shared__ unsigned char bktA[PART_EDGES];
        __shared__ unsigned char bkt_s[PART_EDGES];
        __shared__ unsigned hist[256];
        __shared__ unsigned scanb[256];
        __shared__ unsigned baseg[256];
        __shared__ unsigned cnt[256];
        int tid = threadIdx.x;
        int e0 = blockIdx.x * PART_EDGES;
        hist[tid] = 0;
        cnt[tid] = 0;
        __syncthreads();
#pragma unroll
        for (int k = 0; k < PART_EDGES / 256; ++k) {
            int idx = k * 256 + tid;
            int i = e0 + idx;
            if (i < E) {
                int d = dst[i];
                unsigned b = (unsigned)d >> DB_SHIFT;
                pay_s[idx] = (((unsigned)d & (DB_SIZE - 1)) << 17) | (unsigned)src[i];
                bktA[idx] = (unsigned char)b;
                atomicAdd(&hist[b], 1u);
            }
        }
        __syncthreads();
        unsigned v = hist[tid];
        scanb[tid] = v;
        __syncthreads();
        for (int off = 1; off < 256; off <<= 1) {
            unsigned t = (tid >= off) ? scanb[tid - off] : 0;
            __syncthreads();
            scanb[tid] += t;
            __syncthreads();
        }
        unsigned excl = scanb[tid] - v;
        __syncthreads();
        scanb[tid] = excl;
        if (tid < NDB)
            baseg[tid] = (unsigned)(tid * DB_CAP) + (unsigned)atomicAdd(&db_cursor[tid], (int)v);
        __syncthreads();
#pragma unroll
        for (int k = 0; k < PART_EDGES / 256; ++k) {
            int idx = k * 256 + tid;
            int i = e0 + idx;
            if (i < E) {
                unsigned b = bktA[idx];
                unsigned slot = scanb[b] + atomicAdd(&cnt[b], 1u);
                stage[slot] = pay_s[idx];
                bkt_s[slot] = (unsigned char)b;
            }
        }
        __syncthreads();
        int total = min(PART_EDGES, E - e0);
        for (int j = tid; j < total; j += 256) {
            unsigned b = bkt_s[j];
            unsigned addr = baseg[b] + ((unsigned)j - scanb[b]);
            staged[addr] = stage[j];
        }
    } else {
        gemm_mfma_body<128, 64, 4, 64>(blockIdx.x - NPART, X, W1Th, W1Tl, al, ar, featb, el, er, N);
    }
}

// ---------------- per-bucket LDS counting sort (includes scan of bucket counts) ----------------
__global__ __launch_bounds__(256) void bucket_sort_kernel(
        const unsigned* __restrict__ staged, const int* __restrict__ db_cursor,
        int* __restrict__ csr_src, int* __restrict__ row_ptr, int N, int E) {
    __shared__ unsigned pay[DB_CAP];
    __shared__ int sorted[DB_CAP];
    __shared__ int hist[DB_SIZE];
    __shared__ int excl[DB_SIZE];
    __shared__ int psum[256];
    __shared__ int scn[256];
    int tid = threadIdx.x;
    int k = blockIdx.x;
    // scan the 196 bucket counts to get this bucket's base
    int c = (tid < NDB) ? db_cursor[tid] : 0;
    scn[tid] = c;
    __syncthreads();
    for (int off = 1; off < 256; off <<= 1) {
        int t = (tid >= off) ? scn[tid - off] : 0;
        __syncthreads();
        scn[tid] += t;
        __syncthreads();
    }
    int cnt = db_cursor[k];
    int base = scn[k] - cnt;
    if (k == 0 && tid == 0) row_ptr[N] = E;

    for (int i = tid; i < DB_SIZE; i += 256) hist[i] = 0;
    __syncthreads();
    for (int j = tid; j < cnt; j += 256) {
        unsigned p = staged[(size_t)k * DB_CAP + j];
        pay[j] = p;
        atomicAdd(&hist[p >> 17], 1);
    }
    __syncthreads();
    int s = hist[2 * tid] + hist[2 * tid + 1];
    psum[tid] = s;
    __syncthreads();
    for (int off = 1; off < 256; off <<= 1) {
        int t = (tid >= off) ? psum[tid - off] : 0;
        __syncthreads();
        psum[tid] += t;
        __syncthreads();
    }
    int e0 = psum[tid] - s;
    excl[2 * tid] = e0;
    excl[2 * tid + 1] = e0 + hist[2 * tid];
    __syncthreads();
    for (int i = tid; i < DB_SIZE; i += 256) {
        int d = k * DB_SIZE + i;
        if (d < N) row_ptr[d] = base + excl[i];
    }
    for (int i = tid; i < DB_SIZE; i += 256) hist[i] = 0;
    __syncthreads();
    for (int j = tid; j < cnt; j += 256) {
        unsigned p = pay[j];
        int dl = (int)(p >> 17);
        int pos = excl[dl] + atomicAdd(&hist[dl], 1);
        sorted[pos] = (int)(p & 0x1FFFFu);
    }
    __syncthreads();
    for (int j = tid; j < cnt; j += 256) csr_src[base + j] = sorted[j];
}

// ---------------- gemm2 (thin wrapper over body) ----------------
__global__ __launch_bounds__(256) void gemm2_kernel(
        const float* __restrict__ X,
        const unsigned short* __restrict__ WTh, const unsigned short* __restrict__ WTl,
        const float* __restrict__ al, const float* __restrict__ ar,
        unsigned short* __restrict__ featb, float* __restrict__ el,
        float* __restrict__ er, int N) {
    gemm_mfma_body<64, 40, 3, 48>(blockIdx.x, X, WTh, WTl, al, ar, featb, el, er, N);
}

// ---------------- Segment softmax + aggregation (bf16 gather, fp32 math) ----------------
template <int DOUT, int FSTR, int OSTR, bool ELU>
__global__ void agg_kernel(const int* __restrict__ row_ptr, const int* __restrict__ csr_src,
                           const float* __restrict__ el, const float* __restrict__ er,
                           const unsigned short* __restrict__ featb,
                           const float* __restrict__ bias, float* __restrict__ outp, int N) {
    int lane = threadIdx.x & 63;
    int n = blockIdx.x * (blockDim.x >> 6) + (threadIdx.x >> 6);
    if (n >= N) return;
    int beg = row_ptr[n];
    int end = row_ptr[n + 1];
    int deg = end - beg;
    float ern = er[n];

    constexpr int G2 = DOUT / 4;

    if (deg <= 64) {
        int s = 0;
        float e = -1e30f;
        bool act = lane < deg;
        if (act) {
            s = csr_src[beg + lane];
            e = leaky(el[s] + ern);
        }
        float m = e;
#pragma unroll
        for (int o = 32; o > 0; o >>= 1) m = fmaxf(m, __shfl_xor(m, o, 64));
        float ee = act ? __expf(e - m) : 0.f;
        float ssum = ee;
#pragma unroll
        for (int o = 32; o > 0; o >>= 1) ssum += __shfl_xor(ssum, o, 64);

        int g = lane >> 4;
        int cl = lane & 15;
        float4 acc = make_float4(0.f, 0.f, 0.f, 0.f);
        int niter = (deg + 3) >> 2;
        for (int i = 0; i < niter; i += 2) {
            int e0 = 4 * i + g;
            int e1 = e0 + 4;
            float w0 = __shfl(ee, e0 & 63, 64);
            int s0 = __shfl(s, e0 & 63, 64);
            float w1 = __shfl(ee, e1 & 63, 64);
            int s1 = __shfl(s, e1 & 63, 64);
            if (e0 >= deg) w0 = 0.f;
            if (e1 >= deg) w1 = 0.f;
            if (cl < G2) {
                uint2 q0 = *(reinterpret_cast<const uint2*>(featb + (size_t)s0 * FSTR) + cl);
                uint2 q1 = *(reinterpret_cast<const uint2*>(featb + (size_t)s1 * FSTR) + cl);
                acc.x += w0 * bflo(q0.x) + w1 * bflo(q1.x);
                acc.y += w0 * bfhi(q0.x) + w1 * bfhi(q1.x);
                acc.z += w0 * bflo(q0.y) + w1 * bflo(q1.y);
                acc.w += w0 * bfhi(q0.y) + w1 * bfhi(q1.y);
            }
        }
#pragma unroll
        for (int o = 16; o <= 32; o <<= 1) {
            acc.x += __shfl_xor(acc.x, o, 64);
            acc.y += __shfl_xor(acc.y, o, 64);
            acc.z += __shfl_xor(acc.z, o, 64);
            acc.w += __shfl_xor(acc.w, o, 64);
        }
        if (g == 0 && cl < G2) {
            float inv = (deg > 0) ? 1.f / ssum : 0.f;
            const float4 b4 = reinterpret_cast<const float4*>(bias)[cl];
            float4 o4;
            o4.x = acc.x * inv + b4.x;
            o4.y = acc.y * inv + b4.y;
            o4.z = acc.z * inv + b4.z;
            o4.w = acc.w * inv + b4.w;
            if (ELU) {
                o4.x = o4.x > 0.f ? o4.x : (__expf(o4.x) - 1.f);
                o4.y = o4.y > 0.f ? o4.y : (__expf(o4.y) - 1.f);
                o4.z = o4.z > 0.f ? o4.z : (__expf(o4.z) - 1.f);
                o4.w = o4.w > 0.f ? o4.w : (__expf(o4.w) - 1.f);
            }
            *reinterpret_cast<float4*>(outp + (size_t)n * OSTR + 4 * cl) = o4;
        }
        return;
    }

    // slow path (deg > 64)
    float m = -1e30f;
    for (int j = beg + lane; j < end; j += 64) {
        float e = leaky(el[csr_src[j]] + ern);
        m = fmaxf(m, e);
    }
#pragma unroll
    for (int o = 32; o > 0; o >>= 1) m = fmaxf(m, __shfl_xor(m, o, 64));

    float ssum = 0.f;
    float acc = 0.f;
    for (int base = beg; base < end; base += 64) {
        int j = base + lane;
        int cnt = min(64, end - base);
        int s = (lane < cnt) ? csr_src[j] : 0;
        float ee = 0.f;
        if (lane < cnt) {
            float e = leaky(el[s] + ern);
            ee = __expf(e - m);
        }
        ssum += ee;
        for (int t = 0; t < cnt; ++t) {
            float w = __shfl(ee, t, 64);
            int sj = __shfl(s, t, 64);
            if (lane < DOUT)
                acc += w * __uint_as_float(((unsigned)featb[(size_t)sj * FSTR + lane]) << 16);
        }
    }
#pragma unroll
    for (int o = 32; o > 0; o >>= 1) ssum += __shfl_xor(ssum, o, 64);

    if (lane < DOUT) {
        float o = acc / ssum + bias[lane];
        if (ELU) o = (o > 0.f) ? o : (__expf(o) - 1.f);
        outp[(size_t)n * OSTR + lane] = o;
    }
}

extern "C" void kernel_launch(void* const* d_in, const int* in_sizes, int n_in,
                              void* d_out, int out_size, void* d_ws, size_t ws_size,
                              hipStream_t stream) {
    const float* in_feat = (const float*)d_in[0];
    const int* src = (const int*)d_in[1];
    const int* dst = (const int*)d_in[2];
    const float* W1 = (const float*)d_in[3];
    const float* al1 = (const float*)d_in[4];
    const float* ar1 = (const float*)d_in[5];
    const float* b1 = (const float*)d_in[6];
    const float* W2 = (const float*)d_in[7];
    const float* al2 = (const float*)d_in[8];
    const float* ar2 = (const float*)d_in[9];
    const float* b2 = (const float*)d_in[10];
    float* out = (float*)d_out;

    const int N = N_NODES, E = N_EDGES;

    size_t off = 0;
    auto carve = [&](size_t bytes) {
        void* p = (char*)d_ws + off;
        off += (bytes + 255) & ~(size_t)255;
        return p;
    };
    // long-lived
    unsigned short* featb = (unsigned short*)carve((size_t)N * 64 * 2);  // bf16 gather table
    float* el    = (float*)carve((size_t)N * 4);
    float* er    = (float*)carve((size_t)N * 4);
    int* row_ptr = (int*)carve((size_t)(N + 1) * 4);
    int* csr_src = (int*)carve((size_t)E * 4);
    int* db_cursor = (int*)carve((size_t)NDB * 4);
    unsigned short* W1Th = (unsigned short*)carve((size_t)64 * 128 * 2);
    unsigned short* W1Tl = (unsigned short*)carve((size_t)64 * 128 * 2);
    unsigned short* W2Th = (unsigned short*)carve((size_t)48 * 64 * 2);
    unsigned short* W2Tl = (unsigned short*)carve((size_t)48 * 64 * 2);
    // h overlaps staged (staged dead before agg1 writes h)
    size_t offH = off;
    float* h = (float*)carve((size_t)N * 64 * 4);
    size_t off_end = off;
    off = offH;
    unsigned* staged = (unsigned*)carve((size_t)NDB * DB_CAP * 4);  // 8.0 MB < 25.6 MB
    off = off_end;

    // 1) W conversion (+ db_cursor zeroing)
    wconv2_kernel<<<(64 * 128 + 48 * 64 + 255) / 256, 256, 0, stream>>>(
        W1, W2, W1Th, W1Tl, W2Th, W2Tl, db_cursor);

    // 2) fused: edge partition (782 blocks) + layer-1 MFMA GEMM (1563 blocks)
    fusedA_kernel<<<NPART + NGEMM1, 256, 0, stream>>>(
        src, dst, db_cursor, staged, E,
        in_feat, W1Th, W1Tl, al1, ar1, featb, el, er, N);

    // 3) per-bucket counting sort (scan fused in)
    bucket_sort_kernel<<<NDB, 256, 0, stream>>>(staged, db_cursor, csr_src, row_ptr, N, E);

    int agrid = (N + 3) / 4;

    // 4) layer-1 aggregation
    agg_kernel<64, 64, 64, true><<<agrid, 256, 0, stream>>>(row_ptr, csr_src, el, er, featb, b1, h, N);

    // 5) layer-2 GEMM (padded N=48; featb stride 48)
    gemm2_kernel<<<(N + 63) / 64, 256, 0, stream>>>(h, W2Th, W2Tl, al2, ar2, featb, el, er, N);

    // 6) layer-2 aggregation
    agg_kernel<40, 48, 40, false><<<agrid, 256, 0, stream>>>(row_ptr, csr_src, el, er, featb, b2, out, N);
}

// Round 9
// 269.943 us; speedup vs baseline: 2.2618x; 1.0692x over previous
//
#include <hip/hip_runtime.h>

#define N_NODES 100000
#define N_EDGES 1600000
// dst-keyed two-level counting sort
#define DB_SHIFT 9
#define DB_SIZE 512
#define NDB 196      // ceil(N_NODES / 512)
#define DB_CAP 10240 // per-bucket capacity; mean 8163, std ~90 (seed fixed) -> 23 sigma
#define PART_EDGES 2048
#define NPART ((N_EDGES + PART_EDGES - 1) / PART_EDGES)  // 782
#define NGEMM1 ((N_NODES + 63) / 64)                     // 1563

constexpr float NEG_SLOPE = 0.2f;

__device__ __forceinline__ float leaky(float x) { return x > 0.f ? x : NEG_SLOPE * x; }

__device__ __forceinline__ float bflo(unsigned u) { return __uint_as_float(u << 16); }
__device__ __forceinline__ float bfhi(unsigned u) { return __uint_as_float(u & 0xffff0000u); }

// split fp32 -> bf16 hi (truncate) + bf16 lo (RNE of residual); x ~= hi + lo with ~2^-16 rel err
__device__ __forceinline__ void bfsplit(float x, short& h, short& l) {
    unsigned u = __float_as_uint(x);
    h = (short)(u >> 16);
    float res = x - __uint_as_float(u & 0xffff0000u);
    unsigned r = __float_as_uint(res);
    r = (r + 0x7fffu + ((r >> 16) & 1u)) >> 16;
    l = (short)r;
}

// ---------------- combined W transpose/split (W1 + W2) + db_cursor zeroing ----------------
__global__ void wconv2_kernel(const float* __restrict__ W1, const float* __restrict__ W2,
                              unsigned short* __restrict__ W1Th, unsigned short* __restrict__ W1Tl,
                              unsigned short* __restrict__ W2Th, unsigned short* __restrict__ W2Tl,
                              int* __restrict__ db_cursor) {
    int idx = blockIdx.x * 256 + threadIdx.x;
    if (blockIdx.x == 0 && threadIdx.x < NDB) db_cursor[threadIdx.x] = 0;
    if (idx < 64 * 128) {
        int n = idx / 128, k = idx % 128;
        short h, l;
        bfsplit(W1[(size_t)k * 64 + n], h, l);
        W1Th[idx] = (unsigned short)h;
        W1Tl[idx] = (unsigned short)l;
    } else if (idx < 64 * 128 + 48 * 64) {
        int j = idx - 64 * 128;
        int n = j / 64, k = j % 64;
        float x = (n < 40) ? W2[(size_t)k * 40 + n] : 0.f;
        short h, l;
        bfsplit(x, h, l);
        W2Th[j] = (unsigned short)h;
        W2Tl[j] = (unsigned short)l;
    }
}

// ---------------- MFMA GEMM body (shared by fusedA and gemm2) ----------------
template <int DIN, int NOUT, int NTILES, int OSTR>
__device__ __forceinline__ void gemm_mfma_body(
        int bid, const float* __restrict__ X,
        const unsigned short* __restrict__ WTh, const unsigned short* __restrict__ WTl,
        const float* __restrict__ al, const float* __restrict__ ar,
        unsigned short* __restrict__ featb, float* __restrict__ el,
        float* __restrict__ er, int N) {
    constexpr int KT = DIN / 32;
    using frag = __attribute__((ext_vector_type(8))) short;
    using accv = __attribute__((ext_vector_type(4))) float;

    int lane = threadIdx.x & 63;
    int wid = threadIdx.x >> 6;
    int r0 = (bid * 4 + wid) * 16;
    if (r0 >= N) return;
    int m = lane & 15;
    int quad = lane >> 4;
    int row = r0 + m;
    bool rok = row < N;
    const float* xrow = X + (size_t)(rok ? row : 0) * DIN;

    frag ah[KT], alo[KT];
#pragma unroll
    for (int kt = 0; kt < KT; ++kt) {
        float xv[8];
        if (rok) {
            float4 a0 = *reinterpret_cast<const float4*>(xrow + kt * 32 + quad * 8);
            float4 a1 = *reinterpret_cast<const float4*>(xrow + kt * 32 + quad * 8 + 4);
            xv[0] = a0.x; xv[1] = a0.y; xv[2] = a0.z; xv[3] = a0.w;
            xv[4] = a1.x; xv[5] = a1.y; xv[6] = a1.z; xv[7] = a1.w;
        } else {
#pragma unroll
            for (int j = 0; j < 8; ++j) xv[j] = 0.f;
        }
#pragma unroll
        for (int j = 0; j < 8; ++j) {
            short h, l;
            bfsplit(xv[j], h, l);
            ah[kt][j] = h;
            alo[kt][j] = l;
        }
    }

    accv acc[NTILES];
#pragma unroll
    for (int nt = 0; nt < NTILES; ++nt) acc[nt] = (accv){0.f, 0.f, 0.f, 0.f};

#pragma unroll
    for (int nt = 0; nt < NTILES; ++nt) {
        const unsigned short* bh_base = WTh + (size_t)(nt * 16 + m) * DIN;
        const unsigned short* bl_base = WTl + (size_t)(nt * 16 + m) * DIN;
#pragma unroll
        for (int kt = 0; kt < KT; ++kt) {
            frag bh = *reinterpret_cast<const frag*>(bh_base + kt * 32 + quad * 8);
            frag bl = *reinterpret_cast<const frag*>(bl_base + kt * 32 + quad * 8);
            acc[nt] = __builtin_amdgcn_mfma_f32_16x16x32_bf16(ah[kt], bh, acc[nt], 0, 0, 0);
            acc[nt] = __builtin_amdgcn_mfma_f32_16x16x32_bf16(ah[kt], bl, acc[nt], 0, 0, 0);
            acc[nt] = __builtin_amdgcn_mfma_f32_16x16x32_bf16(alo[kt], bh, acc[nt], 0, 0, 0);
        }
    }

    float pel[4] = {0.f, 0.f, 0.f, 0.f};
    float per[4] = {0.f, 0.f, 0.f, 0.f};
#pragma unroll
    for (int nt = 0; nt < NTILES; ++nt) {
        int n = nt * 16 + m;
        float av = (n < NOUT) ? al[n] : 0.f;
        float rv = (n < NOUT) ? ar[n] : 0.f;
#pragma unroll
        for (int reg = 0; reg < 4; ++reg) {
            float v = acc[nt][reg];
            pel[reg] += v * av;
            per[reg] += v * rv;
            int grow = r0 + quad * 4 + reg;
            if (grow < N && n < NOUT) {
                unsigned u = __float_as_uint(v);
                u = (u + 0x7fffu + ((u >> 16) & 1u)) >> 16;
                featb[(size_t)grow * OSTR + n] = (unsigned short)u;
            }
        }
    }
#pragma unroll
    for (int o = 1; o < 16; o <<= 1) {
#pragma unroll
        for (int reg = 0; reg < 4; ++reg) {
            pel[reg] += __shfl_xor(pel[reg], o, 64);
            per[reg] += __shfl_xor(per[reg], o, 64);
        }
    }
    if (m == 0) {
#pragma unroll
        for (int reg = 0; reg < 4; ++reg) {
            int grow = r0 + quad * 4 + reg;
            if (grow < N) { el[grow] = pel[reg]; er[grow] = per[reg]; }
        }
    }
}

// ---------------- fusedA: partition_dst + gemm1, INTERLEAVED (blockIdx%3==2 -> partition) ----
__global__ __launch_bounds__(256) void fusedA_kernel(
        const int* __restrict__ src, const int* __restrict__ dst,
        int* __restrict__ db_cursor, unsigned* __restrict__ staged, int E,
        const float* __restrict__ X,
        const unsigned short* __restrict__ W1Th, const unsigned short* __restrict__ W1Tl,
        const float* __restrict__ al, const float* __restrict__ ar,
        unsigned short* __restrict__ featb, float* __restrict__ el,
        float* __restrict__ er, int N) {
    int p = blockIdx.x / 3;
    int r = blockIdx.x % 3;
    if (r == 2) {
        // -------- partition by dst>>9; 2048 edges per block; block p --------
        __shared__ unsigned pay_s[PART_EDGES];
        __shared__ unsigned stage[PART_EDGES];
        __shared__ unsigned char bktA[PART_EDGES];
        __shared__ unsigned char bkt_s[PART_EDGES];
        __shared__ unsigned hist[256];
        __shared__ unsigned scanb[256];
        __shared__ unsigned baseg[256];
        __shared__ unsigned cnt[256];
        int tid = threadIdx.x;
        int e0 = p * PART_EDGES;
        hist[tid] = 0;
        cnt[tid] = 0;
        __syncthreads();
#pragma unroll
        for (int k = 0; k < PART_EDGES / 256; ++k) {
            int idx = k * 256 + tid;
            int i = e0 + idx;
            if (i < E) {
                int d = dst[i];
                unsigned b = (unsigned)d >> DB_SHIFT;
                pay_s[idx] = (((unsigned)d & (DB_SIZE - 1)) << 17) | (unsigned)src[i];
                bktA[idx] = (unsigned char)b;
                atomicAdd(&hist[b], 1u);
            }
        }
        __syncthreads();
        unsigned v = hist[tid];
        scanb[tid] = v;
        __syncthreads();
        for (int off = 1; off < 256; off <<= 1) {
            unsigned t = (tid >= off) ? scanb[tid - off] : 0;
            __syncthreads();
            scanb[tid] += t;
            __syncthreads();
        }
        unsigned excl = scanb[tid] - v;
        __syncthreads();
        scanb[tid] = excl;
        if (tid < NDB)
            baseg[tid] = (unsigned)(tid * DB_CAP) + (unsigned)atomicAdd(&db_cursor[tid], (int)v);
        __syncthreads();
#pragma unroll
        for (int k = 0; k < PART_EDGES / 256; ++k) {
            int idx = k * 256 + tid;
            int i = e0 + idx;
            if (i < E) {
                unsigned b = bktA[idx];
                unsigned slot = scanb[b] + atomicAdd(&cnt[b], 1u);
                stage[slot] = pay_s[idx];
                bkt_s[slot] = (unsigned char)b;
            }
        }
        __syncthreads();
        int total = min(PART_EDGES, E - e0);
        for (int j = tid; j < total; j += 256) {
            unsigned b = bkt_s[j];
            unsigned addr = baseg[b] + ((unsigned)j - scanb[b]);
            staged[addr] = stage[j];
        }
    } else {
        // gemm block index: 2 gemm blocks per period of 3
        gemm_mfma_body<128, 64, 4, 64>(2 * p + r, X, W1Th, W1Tl, al, ar, featb, el, er, N);
    }
}

// ---------------- per-bucket LDS counting sort (includes scan of bucket counts) ----------------
__global__ __launch_bounds__(256) void bucket_sort_kernel(
        const unsigned* __restrict__ staged, const int* __restrict__ db_cursor,
        int* __restrict__ csr_src, int* __restrict__ row_ptr, int N, int E) {
    __shared__ unsigned pay[DB_CAP];
    __shared__ int sorted[DB_CAP];
    __shared__ int hist[DB_SIZE];
    __shared__ int excl[DB_SIZE];
    __shared__ int psum[256];
    __shared__ int scn[256];
    int tid = threadIdx.x;
    int k = blockIdx.x;
    int c = (tid < NDB) ? db_cursor[tid] : 0;
    scn[tid] = c;
    __syncthreads();
    for (int off = 1; off < 256; off <<= 1) {
        int t = (tid >= off) ? scn[tid - off] : 0;
        __syncthreads();
        scn[tid] += t;
        __syncthreads();
    }
    int cnt = db_cursor[k];
    int base = scn[k] - cnt;
    if (k == 0 && tid == 0) row_ptr[N] = E;

    for (int i = tid; i < DB_SIZE; i += 256) hist[i] = 0;
    __syncthreads();
    for (int j = tid; j < cnt; j += 256) {
        unsigned p = staged[(size_t)k * DB_CAP + j];
        pay[j] = p;
        atomicAdd(&hist[p >> 17], 1);
    }
    __syncthreads();
    int s = hist[2 * tid] + hist[2 * tid + 1];
    psum[tid] = s;
    __syncthreads();
    for (int off = 1; off < 256; off <<= 1) {
        int t = (tid >= off) ? psum[tid - off] : 0;
        __syncthreads();
        psum[tid] += t;
        __syncthreads();
    }
    int e0 = psum[tid] - s;
    excl[2 * tid] = e0;
    excl[2 * tid + 1] = e0 + hist[2 * tid];
    __syncthreads();
    for (int i = tid; i < DB_SIZE; i += 256) {
        int d = k * DB_SIZE + i;
        if (d < N) row_ptr[d] = base + excl[i];
    }
    for (int i = tid; i < DB_SIZE; i += 256) hist[i] = 0;
    __syncthreads();
    for (int j = tid; j < cnt; j += 256) {
        unsigned p = pay[j];
        int dl = (int)(p >> 17);
        int pos = excl[dl] + atomicAdd(&hist[dl], 1);
        sorted[pos] = (int)(p & 0x1FFFFu);
    }
    __syncthreads();
    for (int j = tid; j < cnt; j += 256) csr_src[base + j] = sorted[j];
}

// ---------------- gemm2 (thin wrapper over body) ----------------
__global__ __launch_bounds__(256) void gemm2_kernel(
        const float* __restrict__ X,
        const unsigned short* __restrict__ WTh, const unsigned short* __restrict__ WTl,
        const float* __restrict__ al, const float* __restrict__ ar,
        unsigned short* __restrict__ featb, float* __restrict__ el,
        float* __restrict__ er, int N) {
    gemm_mfma_body<64, 40, 3, 48>(blockIdx.x, X, WTh, WTl, al, ar, featb, el, er, N);
}

// ---------------- batched gather: NIT iterations, all loads issued before FMAs ----------------
template <int NIT, int G2, int FSTR>
__device__ __forceinline__ void gather_batch(int g, int cl, int s, float ee,
                                             const unsigned short* __restrict__ featb,
                                             float4& acc) {
    float w[NIT];
    int sj[NIT];
#pragma unroll
    for (int i = 0; i < NIT; ++i) {
        int e = 4 * i + g;
        w[i] = __shfl(ee, e, 64);   // ee is 0 for e >= deg
        sj[i] = __shfl(s, e, 64);
    }
    uint2 q[NIT];
#pragma unroll
    for (int i = 0; i < NIT; ++i) {
        q[i] = make_uint2(0u, 0u);
        if (cl < G2)
            q[i] = *(reinterpret_cast<const uint2*>(featb + (size_t)sj[i] * FSTR) + cl);
    }
#pragma unroll
    for (int i = 0; i < NIT; ++i) {
        acc.x += w[i] * bflo(q[i].x);
        acc.y += w[i] * bfhi(q[i].x);
        acc.z += w[i] * bflo(q[i].y);
        acc.w += w[i] * bfhi(q[i].y);
    }
}

// ---------------- Segment softmax + aggregation (bf16 gather, fp32 math) ----------------
template <int DOUT, int FSTR, int OSTR, bool ELU>
__global__ void agg_kernel(const int* __restrict__ row_ptr, const int* __restrict__ csr_src,
                           const float* __restrict__ el, const float* __restrict__ er,
                           const unsigned short* __restrict__ featb,
                           const float* __restrict__ bias, float* __restrict__ outp, int N) {
    int lane = threadIdx.x & 63;
    int n = blockIdx.x * (blockDim.x >> 6) + (threadIdx.x >> 6);
    if (n >= N) return;
    int beg = row_ptr[n];
    int end = row_ptr[n + 1];
    int deg = end - beg;
    float ern = er[n];

    constexpr int G2 = DOUT / 4;

    if (deg <= 64) {
        int s = 0;
        float e = -1e30f;
        bool act = lane < deg;
        if (act) {
            s = csr_src[beg + lane];
            e = leaky(el[s] + ern);
        }
        float m = e;
#pragma unroll
        for (int o = 32; o > 0; o >>= 1) m = fmaxf(m, __shfl_xor(m, o, 64));
        float ee = act ? __expf(e - m) : 0.f;
        float ssum = ee;
#pragma unroll
        for (int o = 32; o > 0; o >>= 1) ssum += __shfl_xor(ssum, o, 64);

        int g = lane >> 4;
        int cl = lane & 15;
        float4 acc = make_float4(0.f, 0.f, 0.f, 0.f);
        if (deg <= 16) {
            gather_batch<4, G2, FSTR>(g, cl, s, ee, featb, acc);
        } else if (deg <= 32) {
            gather_batch<8, G2, FSTR>(g, cl, s, ee, featb, acc);
        } else {
            // rare (deg 33..64): 2-unrolled loop to keep VGPR pressure low
            int niter = (deg + 3) >> 2;
            for (int i = 0; i < niter; i += 2) {
                int e0 = 4 * i + g;
                int e1 = e0 + 4;
                float w0 = __shfl(ee, e0 & 63, 64);
                int s0 = __shfl(s, e0 & 63, 64);
                float w1 = __shfl(ee, e1 & 63, 64);
                int s1 = __shfl(s, e1 & 63, 64);
                if (e1 >= 64) w1 = 0.f;
                if (cl < G2) {
                    uint2 q0 = *(reinterpret_cast<const uint2*>(featb + (size_t)s0 * FSTR) + cl);
                    uint2 q1 = *(reinterpret_cast<const uint2*>(featb + (size_t)s1 * FSTR) + cl);
                    acc.x += w0 * bflo(q0.x) + w1 * bflo(q1.x);
                    acc.y += w0 * bfhi(q0.x) + w1 * bfhi(q1.x);
                    acc.z += w0 * bflo(q0.y) + w1 * bflo(q1.y);
                    acc.w += w0 * bfhi(q0.y) + w1 * bfhi(q1.y);
                }
            }
        }
#pragma unroll
        for (int o = 16; o <= 32; o <<= 1) {
            acc.x += __shfl_xor(acc.x, o, 64);
            acc.y += __shfl_xor(acc.y, o, 64);
            acc.z += __shfl_xor(acc.z, o, 64);
            acc.w += __shfl_xor(acc.w, o, 64);
        }
        if (g == 0 && cl < G2) {
            float inv = (deg > 0) ? 1.f / ssum : 0.f;
            const float4 b4 = reinterpret_cast<const float4*>(bias)[cl];
            float4 o4;
            o4.x = acc.x * inv + b4.x;
            o4.y = acc.y * inv + b4.y;
            o4.z = acc.z * inv + b4.z;
            o4.w = acc.w * inv + b4.w;
            if (ELU) {
                o4.x = o4.x > 0.f ? o4.x : (__expf(o4.x) - 1.f);
                o4.y = o4.y > 0.f ? o4.y : (__expf(o4.y) - 1.f);
                o4.z = o4.z > 0.f ? o4.z : (__expf(o4.z) - 1.f);
                o4.w = o4.w > 0.f ? o4.w : (__expf(o4.w) - 1.f);
            }
            *reinterpret_cast<float4*>(outp + (size_t)n * OSTR + 4 * cl) = o4;
        }
        return;
    }

    // slow path (deg > 64)
    float m = -1e30f;
    for (int j = beg + lane; j < end; j += 64) {
        float e = leaky(el[csr_src[j]] + ern);
        m = fmaxf(m, e);
    }
#pragma unroll
    for (int o = 32; o > 0; o >>= 1) m = fmaxf(m, __shfl_xor(m, o, 64));

    float ssum = 0.f;
    float acc = 0.f;
    for (int base = beg; base < end; base += 64) {
        int j = base + lane;
        int cnt = min(64, end - base);
        int s = (lane < cnt) ? csr_src[j] : 0;
        float ee = 0.f;
        if (lane < cnt) {
            float e = leaky(el[s] + ern);
            ee = __expf(e - m);
        }
        ssum += ee;
        for (int t = 0; t < cnt; ++t) {
            float w = __shfl(ee, t, 64);
            int sj = __shfl(s, t, 64);
            if (lane < DOUT)
                acc += w * __uint_as_float(((unsigned)featb[(size_t)sj * FSTR + lane]) << 16);
        }
    }
#pragma unroll
    for (int o = 32; o > 0; o >>= 1) ssum += __shfl_xor(ssum, o, 64);

    if (lane < DOUT) {
        float o = acc / ssum + bias[lane];
        if (ELU) o = (o > 0.f) ? o : (__expf(o) - 1.f);
        outp[(size_t)n * OSTR + lane] = o;
    }
}

extern "C" void kernel_launch(void* const* d_in, const int* in_sizes, int n_in,
                              void* d_out, int out_size, void* d_ws, size_t ws_size,
                              hipStream_t stream) {
    const float* in_feat = (const float*)d_in[0];
    const int* src = (const int*)d_in[1];
    const int* dst = (const int*)d_in[2];
    const float* W1 = (const float*)d_in[3];
    const float* al1 = (const float*)d_in[4];
    const float* ar1 = (const float*)d_in[5];
    const float* b1 = (const float*)d_in[6];
    const float* W2 = (const float*)d_in[7];
    const float* al2 = (const float*)d_in[8];
    const float* ar2 = (const float*)d_in[9];
    const float* b2 = (const float*)d_in[10];
    float* out = (float*)d_out;

    const int N = N_NODES, E = N_EDGES;

    size_t off = 0;
    auto carve = [&](size_t bytes) {
        void* p = (char*)d_ws + off;
        off += (bytes + 255) & ~(size_t)255;
        return p;
    };
    // long-lived
    unsigned short* featb = (unsigned short*)carve((size_t)N * 64 * 2);  // bf16 gather table
    float* el    = (float*)carve((size_t)N * 4);
    float* er    = (float*)carve((size_t)N * 4);
    int* row_ptr = (int*)carve((size_t)(N + 1) * 4);
    int* csr_src = (int*)carve((size_t)E * 4);
    int* db_cursor = (int*)carve((size_t)NDB * 4);
    unsigned short* W1Th = (unsigned short*)carve((size_t)64 * 128 * 2);
    unsigned short* W1Tl = (unsigned short*)carve((size_t)64 * 128 * 2);
    unsigned short* W2Th = (unsigned short*)carve((size_t)48 * 64 * 2);
    unsigned short* W2Tl = (unsigned short*)carve((size_t)48 * 64 * 2);
    // h overlaps staged (staged dead before agg1 writes h)
    size_t offH = off;
    float* h = (float*)carve((size_t)N * 64 * 4);
    size_t off_end = off;
    off = offH;
    unsigned* staged = (unsigned*)carve((size_t)NDB * DB_CAP * 4);  // 8.0 MB < 25.6 MB
    off = off_end;

    // 1) W conversion (+ db_cursor zeroing)
    wconv2_kernel<<<(64 * 128 + 48 * 64 + 255) / 256, 256, 0, stream>>>(
        W1, W2, W1Th, W1Tl, W2Th, W2Tl, db_cursor);

    // 2) fused + interleaved: partition (1/3 of blocks) + layer-1 MFMA GEMM (2/3)
    fusedA_kernel<<<3 * NPART, 256, 0, stream>>>(
        src, dst, db_cursor, staged, E,
        in_feat, W1Th, W1Tl, al1, ar1, featb, el, er, N);

    // 3) per-bucket counting sort (scan fused in)
    bucket_sort_kernel<<<NDB, 256, 0, stream>>>(staged, db_cursor, csr_src, row_ptr, N, E);

    int agrid = (N + 3) / 4;

    // 4) layer-1 aggregation
    agg_kernel<64, 64, 64, true><<<agrid, 256, 0, stream>>>(row_ptr, csr_src, el, er, featb, b1, h, N);

    // 5) layer-2 GEMM (padded N=48; featb stride 48)
    gemm2_kernel<<<(N + 63) / 64, 256, 0, stream>>>(h, W2Th, W2Tl, al2, ar2, featb, el, er, N);

    // 6) layer-2 aggregation
    agg_kernel<40, 48, 40, false><<<agrid, 256, 0, stream>>>(row_ptr, csr_src, el, er, featb, b2, out, N);
}